// Round 7
// baseline (289.008 us; speedup 1.0000x reference)
//
#include <hip/hip_runtime.h>
#include <math.h>

#define D_MODEL 1024
#define NHEAD   16
#define DKH     64
#define SEQ     2048
#define BATCH   2
#define TOK     (BATCH*SEQ)   // 4096

typedef short s16x8 __attribute__((ext_vector_type(8)));
typedef short s16x4 __attribute__((ext_vector_type(4)));
typedef float f32x4 __attribute__((ext_vector_type(4)));
typedef unsigned short ushort_t;

__device__ inline unsigned short f2bf(float f) {
    union { float f; unsigned u; } v; v.f = f;
    unsigned r = v.u + 0x7FFFu + ((v.u >> 16) & 1u);   // RNE
    return (unsigned short)(r >> 16);
}
__device__ inline float bf2f(ushort_t h) {
    union { unsigned u; float f; } v; v.u = (unsigned)h << 16;
    return v.f;
}
__device__ inline unsigned cvt_pk_bf16(float a, float b) {  // low16=bf16(a), high16=bf16(b)
    unsigned r;
    asm("v_cvt_pk_bf16_f32 %0, %1, %2" : "=v"(r) : "v"(a), "v"(b));
    return r;
}
__device__ inline s16x4 pack_s16x4(float a, float b, float c, float d) {
    unsigned lo = cvt_pk_bf16(a, b), hi = cvt_pk_bf16(c, d);
    s16x4 r;
    r[0] = (short)(lo & 0xffff); r[1] = (short)(lo >> 16);
    r[2] = (short)(hi & 0xffff); r[3] = (short)(hi >> 16);
    return r;
}
__device__ inline void gload16(const void* g, void* l) {
    __builtin_amdgcn_global_load_lds(
        (const __attribute__((address_space(1))) void*)g,
        (__attribute__((address_space(3))) void*)l, 16, 0, 0);
}

// ---------------------------------------------------------------------------
// Weights fp32->bf16 (Wo as hi+lo split) + mask -> float bias (-1e9 / 0).
// ---------------------------------------------------------------------------
__global__ __launch_bounds__(256) void convert_w(
    const float* __restrict__ Wq, const float* __restrict__ Wk,
    const float* __restrict__ Wv, const float* __restrict__ Wo,
    const int* __restrict__ mask,
    ushort_t* __restrict__ Wqb, ushort_t* __restrict__ Wkb,
    ushort_t* __restrict__ Wvb, ushort_t* __restrict__ Wohi,
    ushort_t* __restrict__ Wolo, float* __restrict__ mb)
{
    const int W4 = D_MODEL * D_MODEL / 4;   // 262144
    const int total = 4 * W4 + TOK / 4;
    for (int u = blockIdx.x * 256 + threadIdx.x; u < total; u += gridDim.x * 256) {
        if (u < 3 * W4) {
            int which = u / W4, off = u - which * W4;
            const float* src = which == 0 ? Wq : which == 1 ? Wk : Wv;
            ushort_t*    dst = which == 0 ? Wqb : which == 1 ? Wkb : Wvb;
            float4 f = ((const float4*)src)[off];
            uint2 o;
            o.x = cvt_pk_bf16(f.x, f.y);
            o.y = cvt_pk_bf16(f.z, f.w);
            ((uint2*)dst)[off] = o;
        } else if (u < 4 * W4) {
            int off = u - 3 * W4;
            float4 f = ((const float4*)Wo)[off];
            ushort_t h0 = f2bf(f.x), h1 = f2bf(f.y), h2 = f2bf(f.z), h3 = f2bf(f.w);
            uint2 hw;
            hw.x = (unsigned)h0 | ((unsigned)h1 << 16);
            hw.y = (unsigned)h2 | ((unsigned)h3 << 16);
            ((uint2*)Wohi)[off] = hw;
            uint2 lw;
            lw.x = cvt_pk_bf16(f.x - bf2f(h0), f.y - bf2f(h1));
            lw.y = cvt_pk_bf16(f.z - bf2f(h2), f.w - bf2f(h3));
            ((uint2*)Wolo)[off] = lw;
        } else {
            int off = u - 4 * W4;
            int4 m = ((const int4*)mask)[off];
            float4 f;
            f.x = m.x ? 0.f : -1e9f;
            f.y = m.y ? 0.f : -1e9f;
            f.z = m.z ? 0.f : -1e9f;
            f.w = m.w ? 0.f : -1e9f;
            ((float4*)mb)[off] = f;
        }
    }
}

// ---------------------------------------------------------------------------
// Fused Q/K/V projection GEMM: one dispatch, blockIdx.z selects {q,k,v}.
// BM=128 BN=64 BK=32, 256 thr (2x2 waves, wave-tile 64x32). A fp32 reg-staged
// with cvt to bf16. z<2 -> row-major bf16 out; z==2 -> per-head transposed
// [b][h][d][s] out via LDS transpose (for flash V^T staging).
// ---------------------------------------------------------------------------
__global__ __launch_bounds__(256) void gemm_qkv(
    const float* __restrict__ qin, const float* __restrict__ kin,
    const float* __restrict__ vin,
    const ushort_t* __restrict__ Wqb, const ushort_t* __restrict__ Wkb,
    const ushort_t* __restrict__ Wvb,
    const float* __restrict__ bqp, const float* __restrict__ bkp,
    const float* __restrict__ bvp,
    ushort_t* __restrict__ Qb, ushort_t* __restrict__ Kb,
    ushort_t* __restrict__ Vtb)
{
    __shared__ __align__(16) char pool[64 * 136 * 2];   // >= 12 KiB staging
    ushort_t* As = (ushort_t*)pool;                     // [128][32]
    ushort_t* Ws = As + 128 * 32;                       // [64][32]

    const int z = blockIdx.z;
    const float*    Ain  = z == 0 ? qin : z == 1 ? kin : vin;
    const ushort_t* Wptr = z == 0 ? Wqb : z == 1 ? Wkb : Wvb;
    const float*    bias = z == 0 ? bqp : z == 1 ? bkp : bvp;

    const int t = threadIdx.x;
    const int w = t >> 6, lane = t & 63, l15 = lane & 15, l4 = lane >> 4;
    const int m0 = blockIdx.y * 128, n0 = blockIdx.x * 64;
    const int wr = w >> 1, wc = w & 1;

    f32x4 acc[4][2];
#pragma unroll
    for (int m = 0; m < 4; ++m)
#pragma unroll
        for (int n = 0; n < 2; ++n) acc[m][n] = (f32x4){0.f, 0.f, 0.f, 0.f};

    const ushort_t* Wg = Wptr + (size_t)(n0 + (t >> 2)) * D_MODEL + (t & 3) * 8;
    ushort_t* WsW = Ws + w * 512;
    const float* Ag32 = Ain + (size_t)(m0 + (t >> 1)) * D_MODEL + (t & 1) * 16;

    for (int k0 = 0; k0 < D_MODEL; k0 += 32) {
        __syncthreads();
        {
            const float4* ap = (const float4*)(Ag32 + k0);
            float4 f0 = ap[0], f1 = ap[1], f2 = ap[2], f3 = ap[3];
            uint4 u0, u1;
            u0.x = cvt_pk_bf16(f0.x, f0.y); u0.y = cvt_pk_bf16(f0.z, f0.w);
            u0.z = cvt_pk_bf16(f1.x, f1.y); u0.w = cvt_pk_bf16(f1.z, f1.w);
            u1.x = cvt_pk_bf16(f2.x, f2.y); u1.y = cvt_pk_bf16(f2.z, f2.w);
            u1.z = cvt_pk_bf16(f3.x, f3.y); u1.w = cvt_pk_bf16(f3.z, f3.w);
            uint4* dst = (uint4*)&As[(t >> 1) * 32 + (t & 1) * 16];
            dst[0] = u0; dst[1] = u1;
        }
        gload16(Wg + k0, WsW);
        __syncthreads();

        s16x8 af[4], bfr[2];
#pragma unroll
        for (int m = 0; m < 4; ++m)
            af[m] = *(const s16x8*)&As[(wr * 64 + m * 16 + l15) * 32 + l4 * 8];
#pragma unroll
        for (int n = 0; n < 2; ++n)
            bfr[n] = *(const s16x8*)&Ws[(wc * 32 + n * 16 + l15) * 32 + l4 * 8];
#pragma unroll
        for (int m = 0; m < 4; ++m)
#pragma unroll
            for (int n = 0; n < 2; ++n)
                acc[m][n] = __builtin_amdgcn_mfma_f32_16x16x32_bf16(af[m], bfr[n], acc[m][n], 0, 0, 0);
    }

    if (z == 2) {   // transposed per-head epilogue -> Vtb[b][h][d][s]
        __syncthreads();
        ushort_t* Ct = (ushort_t*)pool;   // [64 d][136 tokens]
#pragma unroll
        for (int n = 0; n < 2; ++n) {
            const int nl = wc * 32 + n * 16 + l15;
            const float bv = bias[n0 + nl];
#pragma unroll
            for (int m = 0; m < 4; ++m) {
                const int ml = wr * 64 + m * 16 + l4 * 4;
#pragma unroll
                for (int r = 0; r < 4; ++r)
                    Ct[nl * 136 + ml + r] = f2bf(acc[m][n][r] + bv);
            }
        }
        __syncthreads();
        const int h  = n0 >> 6;
        const int bb = m0 >> 11;
        const int s0 = m0 & (SEQ - 1);
        const int dl = t >> 2;
        ushort_t* dst = Vtb + (((size_t)bb * NHEAD + h) * DKH + dl) * SEQ + s0;
#pragma unroll
        for (int c = 0; c < 4; ++c) {
            int chk = (t & 3) + c * 4;
            *(uint4*)&dst[chk * 8] = *(const uint4*)&Ct[dl * 136 + chk * 8];
        }
    } else {
        ushort_t* Cout = z == 0 ? Qb : Kb;
#pragma unroll
        for (int n = 0; n < 2; ++n) {
            const int col = n0 + wc * 32 + n * 16 + l15;
            const float bv = bias[col];
#pragma unroll
            for (int m = 0; m < 4; ++m) {
                const int row = m0 + wr * 64 + m * 16 + l4 * 4;
#pragma unroll
                for (int r = 0; r < 4; ++r)
                    Cout[(size_t)(row + r) * D_MODEL + col] = f2bf(acc[m][n][r] + bv);
            }
        }
    }
}

// ---------------------------------------------------------------------------
// Output projection GEMM: C[TOK][D] fp32 = Ctx_bf16 @ (Wohi + Wolo)^T + bias.
// BM=128 BN=64 BK=32, 256 thr, global_load_lds staging (proven round-4 form).
// ---------------------------------------------------------------------------
__global__ __launch_bounds__(256) void gemm_out(
    const ushort_t* __restrict__ Ain, const ushort_t* __restrict__ Wptr,
    const ushort_t* __restrict__ W2ptr, const float* __restrict__ bias,
    float* __restrict__ Cout)
{
    __shared__ ushort_t As[128 * 32];
    __shared__ ushort_t Ws[64 * 32];
    __shared__ ushort_t Ws2[64 * 32];

    const int t = threadIdx.x;
    const int w = t >> 6, lane = t & 63, l15 = lane & 15, l4 = lane >> 4;
    const int m0 = blockIdx.y * 128, n0 = blockIdx.x * 64;
    const int wr = w >> 1, wc = w & 1;

    f32x4 acc[4][2];
#pragma unroll
    for (int m = 0; m < 4; ++m)
#pragma unroll
        for (int n = 0; n < 2; ++n) acc[m][n] = (f32x4){0.f, 0.f, 0.f, 0.f};

    const ushort_t* Ag  = Ain   + (size_t)(m0 + (t >> 2)) * D_MODEL + (t & 3) * 8;
    const ushort_t* Wg  = Wptr  + (size_t)(n0 + (t >> 2)) * D_MODEL + (t & 3) * 8;
    const ushort_t* W2g = W2ptr + (size_t)(n0 + (t >> 2)) * D_MODEL + (t & 3) * 8;
    ushort_t* AsW = As + w * 512;
    ushort_t* WsW = Ws + w * 512;
    ushort_t* Ws2W = Ws2 + w * 512;

    for (int k0 = 0; k0 < D_MODEL; k0 += 32) {
        __syncthreads();
        gload16(Ag + k0, AsW);
        gload16(Ag + (size_t)64 * D_MODEL + k0, AsW + 2048);
        gload16(Wg + k0, WsW);
        gload16(W2g + k0, Ws2W);
        __syncthreads();

        s16x8 af[4], bfr[2], bfr2[2];
#pragma unroll
        for (int m = 0; m < 4; ++m)
            af[m] = *(const s16x8*)&As[(wr * 64 + m * 16 + l15) * 32 + l4 * 8];
#pragma unroll
        for (int n = 0; n < 2; ++n) {
            bfr[n]  = *(const s16x8*)&Ws[(wc * 32 + n * 16 + l15) * 32 + l4 * 8];
            bfr2[n] = *(const s16x8*)&Ws2[(wc * 32 + n * 16 + l15) * 32 + l4 * 8];
        }
#pragma unroll
        for (int m = 0; m < 4; ++m)
#pragma unroll
            for (int n = 0; n < 2; ++n) {
                acc[m][n] = __builtin_amdgcn_mfma_f32_16x16x32_bf16(af[m], bfr[n],  acc[m][n], 0, 0, 0);
                acc[m][n] = __builtin_amdgcn_mfma_f32_16x16x32_bf16(af[m], bfr2[n], acc[m][n], 0, 0, 0);
            }
    }

#pragma unroll
    for (int n = 0; n < 2; ++n) {
        const int col = n0 + wc * 32 + n * 16 + l15;
        const float bv = bias[col];
#pragma unroll
        for (int m = 0; m < 4; ++m) {
            const int row = m0 + wr * 64 + m * 16 + l4 * 4;
#pragma unroll
            for (int r = 0; r < 4; ++r)
                Cout[(size_t)(row + r) * D_MODEL + col] = acc[m][n][r] + bv;
        }
    }
}

// ---------------------------------------------------------------------------
// Flash attention v3 (fixed): 128 thr = 2 waves, 32 q-rows/wave, KV-tile 64.
// Swapped QK^T (mfma(K,Q) -> S^T): P lands row-per-lane -> 4x ds_write_b64.
// FIX vs round-5: P stores are SHORT-typed (alias-compatible with s16x8
// reads -> compiler preserves write->read order) + sched_barrier(0) fence.
// No online max (scores bounded); row-sum + normalize in epilogue.
// ---------------------------------------------------------------------------
__global__ __launch_bounds__(128) void flash3f(
    const ushort_t* __restrict__ Q, const ushort_t* __restrict__ K,
    const ushort_t* __restrict__ Vt, const float* __restrict__ mb,
    ushort_t* __restrict__ Ctx)
{
    __shared__ ushort_t Ks[64 * 72];
    __shared__ ushort_t Vs[64 * 72];
    __shared__ ushort_t Pt[64 * 72];

    const int t = threadIdx.x;
    const int w = t >> 6, lane = t & 63, l15 = lane & 15, l4 = lane >> 4;
    const int q0 = blockIdx.x * 64;
    const int bh = blockIdx.y, b = bh >> 4, h = bh & 15;

    s16x8 qf[2][2];
#pragma unroll
    for (int qb = 0; qb < 2; ++qb) {
        const ushort_t* qp = Q + ((size_t)b * SEQ + q0 + w * 32 + qb * 16 + l15) * D_MODEL + h * DKH + l4 * 8;
        qf[qb][0] = *(const s16x8*)qp;
        qf[qb][1] = *(const s16x8*)(qp + 32);
    }

    f32x4 oacc[2][4];
#pragma unroll
    for (int qb = 0; qb < 2; ++qb)
#pragma unroll
        for (int dt = 0; dt < 4; ++dt) oacc[qb][dt] = (f32x4){0.f, 0.f, 0.f, 0.f};
    float lpart[2] = {0.f, 0.f};

    const int sr = t >> 1;
    const int sc = (t & 1) << 2;
    const ushort_t* Kg = K + (size_t)b * SEQ * D_MODEL + h * DKH;
    const ushort_t* Vg = Vt + ((size_t)bh * DKH + sr) * SEQ;

    uint4 kr[4], vr[4];
#pragma unroll
    for (int c = 0; c < 4; ++c) {
        kr[c] = *(const uint4*)&Kg[(size_t)sr * D_MODEL + (sc + c) * 8];
        vr[c] = *(const uint4*)&Vg[(sc + c) * 8];
    }

    const float CSC = 0.18033688011112042f;   // 0.125 * log2(e)
    const float* mbp = mb + b * SEQ;
    const int prow0 = w * 32 + l15;
    const int krow  = l4 * 8;

    for (int k0 = 0; k0 < SEQ; k0 += 64) {
        __syncthreads();
#pragma unroll
        for (int c = 0; c < 4; ++c) {
            *(uint4*)&Ks[sr * 72 + (sc + c) * 8] = kr[c];
            *(uint4*)&Vs[sr * 72 + (sc + c) * 8] = vr[c];
        }
        __syncthreads();
        if (k0 + 64 < SEQ) {   // prefetch next tile into regs
#pragma unroll
            for (int c = 0; c < 4; ++c) {
                kr[c] = *(const uint4*)&Kg[(size_t)(k0 + 64 + sr) * D_MODEL + (sc + c) * 8];
                vr[c] = *(const uint4*)&Vg[k0 + 64 + (sc + c) * 8];
            }
        }
        float4 mbv[4];
#pragma unroll
        for (int ct = 0; ct < 4; ++ct)
            mbv[ct] = *(const float4*)&mbp[k0 + ct * 16 + l4 * 4];

        // ---- S^T = K Q^T : lane holds S[key=ct*16+l4*4+r][q=l15] ----
        f32x4 sacc[2][4];
#pragma unroll
        for (int qb = 0; qb < 2; ++qb)
#pragma unroll
            for (int ct = 0; ct < 4; ++ct) sacc[qb][ct] = (f32x4){0.f, 0.f, 0.f, 0.f};
#pragma unroll
        for (int ks = 0; ks < 2; ++ks)
#pragma unroll
            for (int ct = 0; ct < 4; ++ct) {
                s16x8 kf = *(const s16x8*)&Ks[(ct * 16 + l15) * 72 + ks * 32 + krow];
                sacc[0][ct] = __builtin_amdgcn_mfma_f32_16x16x32_bf16(kf, qf[0][ks], sacc[0][ct], 0, 0, 0);
                sacc[1][ct] = __builtin_amdgcn_mfma_f32_16x16x32_bf16(kf, qf[1][ks], sacc[1][ct], 0, 0, 0);
            }

        // ---- P = exp2(S*CSC + maskbias); short-typed b64 row writes ----
#pragma unroll
        for (int qb = 0; qb < 2; ++qb) {
#pragma unroll
            for (int ct = 0; ct < 4; ++ct) {
                float p0 = __builtin_amdgcn_exp2f(fmaf(sacc[qb][ct][0], CSC, mbv[ct].x));
                float p1 = __builtin_amdgcn_exp2f(fmaf(sacc[qb][ct][1], CSC, mbv[ct].y));
                float p2 = __builtin_amdgcn_exp2f(fmaf(sacc[qb][ct][2], CSC, mbv[ct].z));
                float p3 = __builtin_amdgcn_exp2f(fmaf(sacc[qb][ct][3], CSC, mbv[ct].w));
                lpart[qb] += (p0 + p1) + (p2 + p3);
                *(s16x4*)&Pt[(prow0 + qb * 16) * 72 + ct * 16 + l4 * 4] =
                    pack_s16x4(p0, p1, p2, p3);
            }
        }
        __builtin_amdgcn_sched_barrier(0);   // pin P-writes before PV reads

        // ---- O += P V : A = Pt rows (q), B = Vs rows (V^T, d) ----
#pragma unroll
        for (int ks = 0; ks < 2; ++ks) {
            s16x8 af0 = *(const s16x8*)&Pt[prow0 * 72 + ks * 32 + krow];
            s16x8 af1 = *(const s16x8*)&Pt[(prow0 + 16) * 72 + ks * 32 + krow];
#pragma unroll
            for (int dt = 0; dt < 4; ++dt) {
                s16x8 vf = *(const s16x8*)&Vs[(dt * 16 + l15) * 72 + ks * 32 + krow];
                oacc[0][dt] = __builtin_amdgcn_mfma_f32_16x16x32_bf16(af0, vf, oacc[0][dt], 0, 0, 0);
                oacc[1][dt] = __builtin_amdgcn_mfma_f32_16x16x32_bf16(af1, vf, oacc[1][dt], 0, 0, 0);
            }
        }
    }

    // ---- epilogue: finish row sums, normalize, store bf16 ctx ----
#pragma unroll
    for (int qb = 0; qb < 2; ++qb) {
        float ls = lpart[qb];
        ls += __shfl_xor(ls, 16);
        ls += __shfl_xor(ls, 32);          // every lane: full sum for q = l15
#pragma unroll
        for (int r = 0; r < 4; ++r) {
            float inv = 1.f / __shfl(ls, l4 * 4 + r);
            const size_t row = (size_t)b * SEQ + q0 + w * 32 + qb * 16 + l4 * 4 + r;
#pragma unroll
            for (int dt = 0; dt < 4; ++dt)
                Ctx[row * D_MODEL + h * DKH + dt * 16 + l15] = f2bf(oacc[qb][dt][r] * inv);
        }
    }
}

extern "C" void kernel_launch(void* const* d_in, const int* in_sizes, int n_in,
                              void* d_out, int out_size, void* d_ws, size_t ws_size,
                              hipStream_t stream) {
    const float* q    = (const float*)d_in[0];
    const float* k    = (const float*)d_in[1];
    const float* v    = (const float*)d_in[2];
    const int*   mask = (const int*)  d_in[3];
    const float* Wq   = (const float*)d_in[4];
    const float* bq   = (const float*)d_in[5];
    const float* Wk   = (const float*)d_in[6];
    const float* bk   = (const float*)d_in[7];
    const float* Wv   = (const float*)d_in[8];
    const float* bv   = (const float*)d_in[9];
    const float* Wo   = (const float*)d_in[10];
    const float* bo   = (const float*)d_in[11];
    float* out = (float*)d_out;

    char* ws = (char*)d_ws;
    ushort_t* Wqb  = (ushort_t*)(ws);
    ushort_t* Wkb  = (ushort_t*)(ws + ( 2u << 20));
    ushort_t* Wvb  = (ushort_t*)(ws + ( 4u << 20));
    ushort_t* Wohi = (ushort_t*)(ws + ( 6u << 20));
    ushort_t* Wolo = (ushort_t*)(ws + ( 8u << 20));
    float*    mb   = (float*)   (ws + (10u << 20));
    ushort_t* Qb   = (ushort_t*)(ws + (12u << 20));
    ushort_t* Kb   = (ushort_t*)(ws + (20u << 20));
    ushort_t* Vtb  = (ushort_t*)(ws + (28u << 20));
    ushort_t* Ctx  = (ushort_t*)(ws + (36u << 20));

    convert_w<<<1024, 256, 0, stream>>>(Wq, Wk, Wv, Wo, mask,
                                        Wqb, Wkb, Wvb, Wohi, Wolo, mb);

    dim3 qkvgrid(D_MODEL / 64, TOK / 128, 3);
    gemm_qkv<<<qkvgrid, 256, 0, stream>>>(q, k, v, Wqb, Wkb, Wvb,
                                          bq, bk, bv, Qb, Kb, Vtb);

    dim3 agrid(SEQ / 64, BATCH * NHEAD);
    flash3f<<<agrid, 128, 0, stream>>>(Qb, Kb, Vtb, mb, Ctx);

    dim3 ogrid(D_MODEL / 64, TOK / 128);
    gemm_out<<<ogrid, 256, 0, stream>>>(Ctx, Wohi, Wolo, bo, out);
}

// Round 8
// 188.923 us; speedup vs baseline: 1.5298x; 1.5298x over previous
//
#include <hip/hip_runtime.h>
#include <math.h>

#define D_MODEL 1024
#define NHEAD   16
#define DKH     64
#define SEQ     2048
#define BATCH   2
#define TOK     (BATCH*SEQ)   // 4096

typedef short s16x8 __attribute__((ext_vector_type(8)));
typedef float f32x4 __attribute__((ext_vector_type(4)));
typedef unsigned short ushort_t;

__device__ inline unsigned short f2bf(float f) {
    union { float f; unsigned u; } v; v.f = f;
    unsigned r = v.u + 0x7FFFu + ((v.u >> 16) & 1u);   // RNE
    return (unsigned short)(r >> 16);
}
__device__ inline float bf2f(ushort_t h) {
    union { unsigned u; float f; } v; v.u = (unsigned)h << 16;
    return v.f;
}
__device__ inline unsigned cvt_pk_bf16(float a, float b) {  // low16=bf16(a), high16=bf16(b)
    unsigned r;
    asm("v_cvt_pk_bf16_f32 %0, %1, %2" : "=v"(r) : "v"(a), "v"(b));
    return r;
}
__device__ inline void gload16(const void* g, void* l) {
    __builtin_amdgcn_global_load_lds(
        (const __attribute__((address_space(1))) void*)g,
        (__attribute__((address_space(3))) void*)l, 16, 0, 0);
}

// ---------------------------------------------------------------------------
// Weights fp32->bf16 (Wo as hi+lo split) + mask -> float bias (-1e9 / 0).
// ---------------------------------------------------------------------------
__global__ __launch_bounds__(256) void convert_w(
    const float* __restrict__ Wq, const float* __restrict__ Wk,
    const float* __restrict__ Wv, const float* __restrict__ Wo,
    const int* __restrict__ mask,
    ushort_t* __restrict__ Wqb, ushort_t* __restrict__ Wkb,
    ushort_t* __restrict__ Wvb, ushort_t* __restrict__ Wohi,
    ushort_t* __restrict__ Wolo, float* __restrict__ mb)
{
    const int W4 = D_MODEL * D_MODEL / 4;   // 262144
    const int total = 4 * W4 + TOK / 4;
    for (int u = blockIdx.x * 256 + threadIdx.x; u < total; u += gridDim.x * 256) {
        if (u < 3 * W4) {
            int which = u / W4, off = u - which * W4;
            const float* src = which == 0 ? Wq : which == 1 ? Wk : Wv;
            ushort_t*    dst = which == 0 ? Wqb : which == 1 ? Wkb : Wvb;
            float4 f = ((const float4*)src)[off];
            uint2 o;
            o.x = cvt_pk_bf16(f.x, f.y);
            o.y = cvt_pk_bf16(f.z, f.w);
            ((uint2*)dst)[off] = o;
        } else if (u < 4 * W4) {
            int off = u - 3 * W4;
            float4 f = ((const float4*)Wo)[off];
            ushort_t h0 = f2bf(f.x), h1 = f2bf(f.y), h2 = f2bf(f.z), h3 = f2bf(f.w);
            uint2 hw;
            hw.x = (unsigned)h0 | ((unsigned)h1 << 16);
            hw.y = (unsigned)h2 | ((unsigned)h3 << 16);
            ((uint2*)Wohi)[off] = hw;
            uint2 lw;
            lw.x = cvt_pk_bf16(f.x - bf2f(h0), f.y - bf2f(h1));
            lw.y = cvt_pk_bf16(f.z - bf2f(h2), f.w - bf2f(h3));
            ((uint2*)Wolo)[off] = lw;
        } else {
            int off = u - 4 * W4;
            int4 m = ((const int4*)mask)[off];
            float4 f;
            f.x = m.x ? 0.f : -1e9f;
            f.y = m.y ? 0.f : -1e9f;
            f.z = m.z ? 0.f : -1e9f;
            f.w = m.w ? 0.f : -1e9f;
            ((float4*)mb)[off] = f;
        }
    }
}

// ---------------------------------------------------------------------------
// Fused Q/K/V projection GEMM: one dispatch, blockIdx.z selects {q,k,v}.
// BM=128 BN=64 BK=32, 256 thr (2x2 waves, wave-tile 64x32). A fp32 reg-staged
// with cvt to bf16. z<2 -> row-major bf16 out; z==2 -> per-head transposed
// [b][h][d][s] out via LDS transpose (for flash V^T staging).
// ---------------------------------------------------------------------------
__global__ __launch_bounds__(256) void gemm_qkv(
    const float* __restrict__ qin, const float* __restrict__ kin,
    const float* __restrict__ vin,
    const ushort_t* __restrict__ Wqb, const ushort_t* __restrict__ Wkb,
    const ushort_t* __restrict__ Wvb,
    const float* __restrict__ bqp, const float* __restrict__ bkp,
    const float* __restrict__ bvp,
    ushort_t* __restrict__ Qb, ushort_t* __restrict__ Kb,
    ushort_t* __restrict__ Vtb)
{
    __shared__ __align__(16) char pool[64 * 136 * 2];   // >= 12 KiB staging
    ushort_t* As = (ushort_t*)pool;                     // [128][32]
    ushort_t* Ws = As + 128 * 32;                       // [64][32]

    const int z = blockIdx.z;
    const float*    Ain  = z == 0 ? qin : z == 1 ? kin : vin;
    const ushort_t* Wptr = z == 0 ? Wqb : z == 1 ? Wkb : Wvb;
    const float*    bias = z == 0 ? bqp : z == 1 ? bkp : bvp;

    const int t = threadIdx.x;
    const int w = t >> 6, lane = t & 63, l15 = lane & 15, l4 = lane >> 4;
    const int m0 = blockIdx.y * 128, n0 = blockIdx.x * 64;
    const int wr = w >> 1, wc = w & 1;

    f32x4 acc[4][2];
#pragma unroll
    for (int m = 0; m < 4; ++m)
#pragma unroll
        for (int n = 0; n < 2; ++n) acc[m][n] = (f32x4){0.f, 0.f, 0.f, 0.f};

    const ushort_t* Wg = Wptr + (size_t)(n0 + (t >> 2)) * D_MODEL + (t & 3) * 8;
    ushort_t* WsW = Ws + w * 512;
    const float* Ag32 = Ain + (size_t)(m0 + (t >> 1)) * D_MODEL + (t & 1) * 16;

    for (int k0 = 0; k0 < D_MODEL; k0 += 32) {
        __syncthreads();
        {
            const float4* ap = (const float4*)(Ag32 + k0);
            float4 f0 = ap[0], f1 = ap[1], f2 = ap[2], f3 = ap[3];
            uint4 u0, u1;
            u0.x = cvt_pk_bf16(f0.x, f0.y); u0.y = cvt_pk_bf16(f0.z, f0.w);
            u0.z = cvt_pk_bf16(f1.x, f1.y); u0.w = cvt_pk_bf16(f1.z, f1.w);
            u1.x = cvt_pk_bf16(f2.x, f2.y); u1.y = cvt_pk_bf16(f2.z, f2.w);
            u1.z = cvt_pk_bf16(f3.x, f3.y); u1.w = cvt_pk_bf16(f3.z, f3.w);
            uint4* dst = (uint4*)&As[(t >> 1) * 32 + (t & 1) * 16];
            dst[0] = u0; dst[1] = u1;
        }
        gload16(Wg + k0, WsW);
        __syncthreads();

        s16x8 af[4], bfr[2];
#pragma unroll
        for (int m = 0; m < 4; ++m)
            af[m] = *(const s16x8*)&As[(wr * 64 + m * 16 + l15) * 32 + l4 * 8];
#pragma unroll
        for (int n = 0; n < 2; ++n)
            bfr[n] = *(const s16x8*)&Ws[(wc * 32 + n * 16 + l15) * 32 + l4 * 8];
#pragma unroll
        for (int m = 0; m < 4; ++m)
#pragma unroll
            for (int n = 0; n < 2; ++n)
                acc[m][n] = __builtin_amdgcn_mfma_f32_16x16x32_bf16(af[m], bfr[n], acc[m][n], 0, 0, 0);
    }

    if (z == 2) {   // transposed per-head epilogue -> Vtb[b][h][d][s]
        __syncthreads();
        ushort_t* Ct = (ushort_t*)pool;   // [64 d][136 tokens]
#pragma unroll
        for (int n = 0; n < 2; ++n) {
            const int nl = wc * 32 + n * 16 + l15;
            const float bv = bias[n0 + nl];
#pragma unroll
            for (int m = 0; m < 4; ++m) {
                const int ml = wr * 64 + m * 16 + l4 * 4;
#pragma unroll
                for (int r = 0; r < 4; ++r)
                    Ct[nl * 136 + ml + r] = f2bf(acc[m][n][r] + bv);
            }
        }
        __syncthreads();
        const int h  = n0 >> 6;
        const int bb = m0 >> 11;
        const int s0 = m0 & (SEQ - 1);
        const int dl = t >> 2;
        ushort_t* dst = Vtb + (((size_t)bb * NHEAD + h) * DKH + dl) * SEQ + s0;
#pragma unroll
        for (int c = 0; c < 4; ++c) {
            int chk = (t & 3) + c * 4;
            *(uint4*)&dst[chk * 8] = *(const uint4*)&Ct[dl * 136 + chk * 8];
        }
    } else {
        ushort_t* Cout = z == 0 ? Qb : Kb;
#pragma unroll
        for (int n = 0; n < 2; ++n) {
            const int col = n0 + wc * 32 + n * 16 + l15;
            const float bv = bias[col];
#pragma unroll
            for (int m = 0; m < 4; ++m) {
                const int row = m0 + wr * 64 + m * 16 + l4 * 4;
#pragma unroll
                for (int r = 0; r < 4; ++r)
                    Cout[(size_t)(row + r) * D_MODEL + col] = f2bf(acc[m][n][r] + bv);
            }
        }
    }
}

// ---------------------------------------------------------------------------
// Output projection GEMM: C[TOK][D] fp32 = Ctx_bf16 @ (Wohi + Wolo)^T + bias.
// BM=128 BN=64 BK=32, 256 thr, global_load_lds staging (proven round-4 form).
// ---------------------------------------------------------------------------
__global__ __launch_bounds__(256) void gemm_out(
    const ushort_t* __restrict__ Ain, const ushort_t* __restrict__ Wptr,
    const ushort_t* __restrict__ W2ptr, const float* __restrict__ bias,
    float* __restrict__ Cout)
{
    __shared__ ushort_t As[128 * 32];
    __shared__ ushort_t Ws[64 * 32];
    __shared__ ushort_t Ws2[64 * 32];

    const int t = threadIdx.x;
    const int w = t >> 6, lane = t & 63, l15 = lane & 15, l4 = lane >> 4;
    const int m0 = blockIdx.y * 128, n0 = blockIdx.x * 64;
    const int wr = w >> 1, wc = w & 1;

    f32x4 acc[4][2];
#pragma unroll
    for (int m = 0; m < 4; ++m)
#pragma unroll
        for (int n = 0; n < 2; ++n) acc[m][n] = (f32x4){0.f, 0.f, 0.f, 0.f};

    const ushort_t* Ag  = Ain   + (size_t)(m0 + (t >> 2)) * D_MODEL + (t & 3) * 8;
    const ushort_t* Wg  = Wptr  + (size_t)(n0 + (t >> 2)) * D_MODEL + (t & 3) * 8;
    const ushort_t* W2g = W2ptr + (size_t)(n0 + (t >> 2)) * D_MODEL + (t & 3) * 8;
    ushort_t* AsW = As + w * 512;
    ushort_t* WsW = Ws + w * 512;
    ushort_t* Ws2W = Ws2 + w * 512;

    for (int k0 = 0; k0 < D_MODEL; k0 += 32) {
        __syncthreads();
        gload16(Ag + k0, AsW);
        gload16(Ag + (size_t)64 * D_MODEL + k0, AsW + 2048);
        gload16(Wg + k0, WsW);
        gload16(W2g + k0, Ws2W);
        __syncthreads();

        s16x8 af[4], bfr[2], bfr2[2];
#pragma unroll
        for (int m = 0; m < 4; ++m)
            af[m] = *(const s16x8*)&As[(wr * 64 + m * 16 + l15) * 32 + l4 * 8];
#pragma unroll
        for (int n = 0; n < 2; ++n) {
            bfr[n]  = *(const s16x8*)&Ws[(wc * 32 + n * 16 + l15) * 32 + l4 * 8];
            bfr2[n] = *(const s16x8*)&Ws2[(wc * 32 + n * 16 + l15) * 32 + l4 * 8];
        }
#pragma unroll
        for (int m = 0; m < 4; ++m)
#pragma unroll
            for (int n = 0; n < 2; ++n) {
                acc[m][n] = __builtin_amdgcn_mfma_f32_16x16x32_bf16(af[m], bfr[n],  acc[m][n], 0, 0, 0);
                acc[m][n] = __builtin_amdgcn_mfma_f32_16x16x32_bf16(af[m], bfr2[n], acc[m][n], 0, 0, 0);
            }
    }

#pragma unroll
    for (int n = 0; n < 2; ++n) {
        const int col = n0 + wc * 32 + n * 16 + l15;
        const float bv = bias[col];
#pragma unroll
        for (int m = 0; m < 4; ++m) {
            const int row = m0 + wr * 64 + m * 16 + l4 * 4;
#pragma unroll
            for (int r = 0; r < 4; ++r)
                Cout[(size_t)(row + r) * D_MODEL + col] = acc[m][n][r] + bv;
        }
    }
}

// ---------------------------------------------------------------------------
// Flash attention (verified round-4 flash2, byte-identical inner loop).
// ONE change: grid is (x=bh, y=qtile) so all 32 q-tile blocks of a head land
// on the same XCD (block-id % 8 == bh % 8) -> K/V stay resident in that
// XCD's 4MB L2 (4 heads x 512KB). Pure index remap.
// ---------------------------------------------------------------------------
__global__ __launch_bounds__(256) void flash2(
    const ushort_t* __restrict__ Q, const ushort_t* __restrict__ K,
    const ushort_t* __restrict__ Vt, const float* __restrict__ mb,
    ushort_t* __restrict__ Ctx)
{
    __shared__ ushort_t Ks[64 * 72];
    __shared__ ushort_t Vs[64 * 72];
    __shared__ ushort_t Ps[64 * 72];

    const int t = threadIdx.x;
    const int w = t >> 6, lane = t & 63, l15 = lane & 15, l4 = lane >> 4;
    const int q0 = blockIdx.y * 64;                  // qtile now on y
    const int bh = blockIdx.x, b = bh >> 4, h = bh & 15;   // bh now on x

    s16x8 qf0, qf1;
    {
        const ushort_t* qp = Q + ((size_t)b * SEQ + q0 + w * 16 + l15) * D_MODEL + h * DKH + l4 * 8;
        qf0 = *(const s16x8*)qp;
        qf1 = *(const s16x8*)(qp + 32);
    }

    f32x4 oacc[4];
#pragma unroll
    for (int dt = 0; dt < 4; ++dt) oacc[dt] = (f32x4){0.f, 0.f, 0.f, 0.f};
    float lpart[4] = {0.f, 0.f, 0.f, 0.f};

    const int ch   = t & 7;
    const int row0 = t >> 3;
    const ushort_t* Kg = K  + ((size_t)b * SEQ) * D_MODEL + h * DKH + ch * 8;
    const ushort_t* Vg = Vt + ((size_t)bh * DKH) * SEQ + ch * 8;

    uint4 kr0 = *(const uint4*)&Kg[(size_t)row0 * D_MODEL];
    uint4 kr1 = *(const uint4*)&Kg[(size_t)(row0 + 32) * D_MODEL];
    uint4 vr0 = *(const uint4*)&Vg[(size_t)row0 * SEQ];
    uint4 vr1 = *(const uint4*)&Vg[(size_t)(row0 + 32) * SEQ];

    const float CSC = 0.18033688011112042f;   // 0.125 * log2(e)
    const float* mbp = mb + b * SEQ;

    for (int k0 = 0; k0 < SEQ; k0 += 64) {
        __syncthreads();
        *(uint4*)&Ks[row0 * 72 + ch * 8]        = kr0;
        *(uint4*)&Ks[(row0 + 32) * 72 + ch * 8] = kr1;
        *(uint4*)&Vs[row0 * 72 + ch * 8]        = vr0;
        *(uint4*)&Vs[(row0 + 32) * 72 + ch * 8] = vr1;
        __syncthreads();
        if (k0 + 64 < SEQ) {
            kr0 = *(const uint4*)&Kg[(size_t)(k0 + 64 + row0) * D_MODEL];
            kr1 = *(const uint4*)&Kg[(size_t)(k0 + 64 + row0 + 32) * D_MODEL];
            vr0 = *(const uint4*)&Vg[(size_t)row0 * SEQ + k0 + 64];
            vr1 = *(const uint4*)&Vg[(size_t)(row0 + 32) * SEQ + k0 + 64];
        }
        float mbv[4];
#pragma unroll
        for (int ct = 0; ct < 4; ++ct) mbv[ct] = mbp[k0 + ct * 16 + l15];

        f32x4 sacc[4];
#pragma unroll
        for (int ct = 0; ct < 4; ++ct) sacc[ct] = (f32x4){0.f, 0.f, 0.f, 0.f};
#pragma unroll
        for (int ct = 0; ct < 4; ++ct) {
            s16x8 b0 = *(const s16x8*)&Ks[(ct * 16 + l15) * 72 + l4 * 8];
            s16x8 b1 = *(const s16x8*)&Ks[(ct * 16 + l15) * 72 + 32 + l4 * 8];
            sacc[ct] = __builtin_amdgcn_mfma_f32_16x16x32_bf16(qf0, b0, sacc[ct], 0, 0, 0);
            sacc[ct] = __builtin_amdgcn_mfma_f32_16x16x32_bf16(qf1, b1, sacc[ct], 0, 0, 0);
        }

#pragma unroll
        for (int ct = 0; ct < 4; ++ct) {
            float p0 = __builtin_amdgcn_exp2f(fmaf(sacc[ct][0], CSC, mbv[ct]));
            float p1 = __builtin_amdgcn_exp2f(fmaf(sacc[ct][1], CSC, mbv[ct]));
            float p2 = __builtin_amdgcn_exp2f(fmaf(sacc[ct][2], CSC, mbv[ct]));
            float p3 = __builtin_amdgcn_exp2f(fmaf(sacc[ct][3], CSC, mbv[ct]));
            lpart[0] += p0; lpart[1] += p1; lpart[2] += p2; lpart[3] += p3;
            unsigned u01 = cvt_pk_bf16(p0, p1);
            unsigned u23 = cvt_pk_bf16(p2, p3);
            int base = (w * 16 + l4 * 4) * 72 + ct * 16 + l15;
            Ps[base]       = (ushort_t)u01;
            Ps[base + 72]  = (ushort_t)(u01 >> 16);
            Ps[base + 144] = (ushort_t)u23;
            Ps[base + 216] = (ushort_t)(u23 >> 16);
        }

#pragma unroll
        for (int ks = 0; ks < 2; ++ks) {
            s16x8 af = *(const s16x8*)&Ps[(w * 16 + l15) * 72 + ks * 32 + l4 * 8];
#pragma unroll
            for (int dt = 0; dt < 4; ++dt) {
                s16x8 bf = *(const s16x8*)&Vs[(dt * 16 + l15) * 72 + ks * 32 + l4 * 8];
                oacc[dt] = __builtin_amdgcn_mfma_f32_16x16x32_bf16(af, bf, oacc[dt], 0, 0, 0);
            }
        }
    }

#pragma unroll
    for (int r = 0; r < 4; ++r) {
        lpart[r] += __shfl_xor(lpart[r], 1);
        lpart[r] += __shfl_xor(lpart[r], 2);
        lpart[r] += __shfl_xor(lpart[r], 4);
        lpart[r] += __shfl_xor(lpart[r], 8);
    }
    const size_t obase = ((size_t)b * SEQ + q0 + w * 16 + l4 * 4) * D_MODEL + h * DKH + l15;
#pragma unroll
    for (int r = 0; r < 4; ++r) {
        float inv = 1.f / lpart[r];
#pragma unroll
        for (int dt = 0; dt < 4; ++dt)
            Ctx[obase + (size_t)r * D_MODEL + dt * 16] = f2bf(oacc[dt][r] * inv);
    }
}

extern "C" void kernel_launch(void* const* d_in, const int* in_sizes, int n_in,
                              void* d_out, int out_size, void* d_ws, size_t ws_size,
                              hipStream_t stream) {
    const float* q    = (const float*)d_in[0];
    const float* k    = (const float*)d_in[1];
    const float* v    = (const float*)d_in[2];
    const int*   mask = (const int*)  d_in[3];
    const float* Wq   = (const float*)d_in[4];
    const float* bq   = (const float*)d_in[5];
    const float* Wk   = (const float*)d_in[6];
    const float* bk   = (const float*)d_in[7];
    const float* Wv   = (const float*)d_in[8];
    const float* bv   = (const float*)d_in[9];
    const float* Wo   = (const float*)d_in[10];
    const float* bo   = (const float*)d_in[11];
    float* out = (float*)d_out;

    char* ws = (char*)d_ws;
    ushort_t* Wqb  = (ushort_t*)(ws);
    ushort_t* Wkb  = (ushort_t*)(ws + ( 2u << 20));
    ushort_t* Wvb  = (ushort_t*)(ws + ( 4u << 20));
    ushort_t* Wohi = (ushort_t*)(ws + ( 6u << 20));
    ushort_t* Wolo = (ushort_t*)(ws + ( 8u << 20));
    float*    mb   = (float*)   (ws + (10u << 20));
    ushort_t* Qb   = (ushort_t*)(ws + (12u << 20));
    ushort_t* Kb   = (ushort_t*)(ws + (20u << 20));
    ushort_t* Vtb  = (ushort_t*)(ws + (28u << 20));
    ushort_t* Ctx  = (ushort_t*)(ws + (36u << 20));

    convert_w<<<1024, 256, 0, stream>>>(Wq, Wk, Wv, Wo, mask,
                                        Wqb, Wkb, Wvb, Wohi, Wolo, mb);

    dim3 qkvgrid(D_MODEL / 64, TOK / 128, 3);
    gemm_qkv<<<qkvgrid, 256, 0, stream>>>(q, k, v, Wqb, Wkb, Wvb,
                                          bq, bk, bv, Qb, Kb, Vtb);

    dim3 agrid(BATCH * NHEAD, SEQ / 64);   // x=bh -> XCD-local K/V reuse
    flash2<<<agrid, 256, 0, stream>>>(Qb, Kb, Vtb, mb, Ctx);

    dim3 ogrid(D_MODEL / 64, TOK / 128);
    gemm_out<<<ogrid, 256, 0, stream>>>(Ctx, Wohi, Wolo, bo, out);
}

// Round 9
// 179.357 us; speedup vs baseline: 1.6114x; 1.0533x over previous
//
#include <hip/hip_runtime.h>
#include <math.h>

#define D_MODEL 1024
#define NHEAD   16
#define DKH     64
#define SEQ     2048
#define BATCH   2
#define TOK     (BATCH*SEQ)   // 4096

typedef short s16x8 __attribute__((ext_vector_type(8)));
typedef float f32x4 __attribute__((ext_vector_type(4)));
typedef unsigned short ushort_t;

__device__ inline unsigned short f2bf(float f) {
    union { float f; unsigned u; } v; v.f = f;
    unsigned r = v.u + 0x7FFFu + ((v.u >> 16) & 1u);   // RNE
    return (unsigned short)(r >> 16);
}
__device__ inline float bf2f(ushort_t h) {
    union { unsigned u; float f; } v; v.u = (unsigned)h << 16;
    return v.f;
}
__device__ inline unsigned cvt_pk_bf16(float a, float b) {  // low16=bf16(a), high16=bf16(b)
    unsigned r;
    asm("v_cvt_pk_bf16_f32 %0, %1, %2" : "=v"(r) : "v"(a), "v"(b));
    return r;
}
__device__ inline void gload16(const void* g, void* l) {
    __builtin_amdgcn_global_load_lds(
        (const __attribute__((address_space(1))) void*)g,
        (__attribute__((address_space(3))) void*)l, 16, 0, 0);
}

// ---------------------------------------------------------------------------
// Weights fp32->bf16 (Wo as hi+lo split) + mask -> float bias (-1e9 / 0).
// ---------------------------------------------------------------------------
__global__ __launch_bounds__(256) void convert_w(
    const float* __restrict__ Wq, const float* __restrict__ Wk,
    const float* __restrict__ Wv, const float* __restrict__ Wo,
    const int* __restrict__ mask,
    ushort_t* __restrict__ Wqb, ushort_t* __restrict__ Wkb,
    ushort_t* __restrict__ Wvb, ushort_t* __restrict__ Wohi,
    ushort_t* __restrict__ Wolo, float* __restrict__ mb)
{
    const int W4 = D_MODEL * D_MODEL / 4;   // 262144
    const int total = 4 * W4 + TOK / 4;
    for (int u = blockIdx.x * 256 + threadIdx.x; u < total; u += gridDim.x * 256) {
        if (u < 3 * W4) {
            int which = u / W4, off = u - which * W4;
            const float* src = which == 0 ? Wq : which == 1 ? Wk : Wv;
            ushort_t*    dst = which == 0 ? Wqb : which == 1 ? Wkb : Wvb;
            float4 f = ((const float4*)src)[off];
            uint2 o;
            o.x = cvt_pk_bf16(f.x, f.y);
            o.y = cvt_pk_bf16(f.z, f.w);
            ((uint2*)dst)[off] = o;
        } else if (u < 4 * W4) {
            int off = u - 3 * W4;
            float4 f = ((const float4*)Wo)[off];
            ushort_t h0 = f2bf(f.x), h1 = f2bf(f.y), h2 = f2bf(f.z), h3 = f2bf(f.w);
            uint2 hw;
            hw.x = (unsigned)h0 | ((unsigned)h1 << 16);
            hw.y = (unsigned)h2 | ((unsigned)h3 << 16);
            ((uint2*)Wohi)[off] = hw;
            uint2 lw;
            lw.x = cvt_pk_bf16(f.x - bf2f(h0), f.y - bf2f(h1));
            lw.y = cvt_pk_bf16(f.z - bf2f(h2), f.w - bf2f(h3));
            ((uint2*)Wolo)[off] = lw;
        } else {
            int off = u - 4 * W4;
            int4 m = ((const int4*)mask)[off];
            float4 f;
            f.x = m.x ? 0.f : -1e9f;
            f.y = m.y ? 0.f : -1e9f;
            f.z = m.z ? 0.f : -1e9f;
            f.w = m.w ? 0.f : -1e9f;
            ((float4*)mb)[off] = f;
        }
    }
}

// ---------------------------------------------------------------------------
// Fused Q/K/V projection GEMM: blockIdx.z selects {q,k,v}.
// BM=128 BN=128 BK=32, 256 thr, wave-tile 64x64 (16 MFMA/K-step, m97 shape).
// Chunked XCD swizzle: hwid -> (hwid%8)*32 + hwid/8, so each XCD owns 4
// contiguous m-slabs for ALL n-tiles -> A-slab fetched once per XCD (L2-hit).
// A fp32 reg-staged to bf16. z<2 -> row-major bf16; z==2 -> [b][h][d][s].
// ---------------------------------------------------------------------------
__global__ __launch_bounds__(256) void gemm_qkv(
    const float* __restrict__ qin, const float* __restrict__ kin,
    const float* __restrict__ vin,
    const ushort_t* __restrict__ Wqb, const ushort_t* __restrict__ Wkb,
    const ushort_t* __restrict__ Wvb,
    const float* __restrict__ bqp, const float* __restrict__ bkp,
    const float* __restrict__ bvp,
    ushort_t* __restrict__ Qb, ushort_t* __restrict__ Kb,
    ushort_t* __restrict__ Vtb)
{
    __shared__ __align__(16) char pool[64 * 136 * 2];   // >=16KB staging, 17KB epi
    ushort_t* As = (ushort_t*)pool;                     // [128][32]
    ushort_t* Ws = As + 128 * 32;                       // [128][32]

    const int z = blockIdx.z;
    const float*    Ain  = z == 0 ? qin : z == 1 ? kin : vin;
    const ushort_t* Wptr = z == 0 ? Wqb : z == 1 ? Wkb : Wvb;
    const float*    bias = z == 0 ? bqp : z == 1 ? bkp : bvp;

    // bijective chunked XCD swizzle over the 8x32 (x,y) grid
    const int hwid = blockIdx.x + 8 * blockIdx.y;       // 0..255, XCD = hwid%8
    const int work = (hwid & 7) * 32 + (hwid >> 3);
    const int m0 = (work >> 3) * 128;                   // y-tile
    const int n0 = (work & 7) * 128;                    // x-tile

    const int t = threadIdx.x;
    const int w = t >> 6, lane = t & 63, l15 = lane & 15, l4 = lane >> 4;
    const int wr = w >> 1, wc = w & 1;

    f32x4 acc[4][4];
#pragma unroll
    for (int m = 0; m < 4; ++m)
#pragma unroll
        for (int n = 0; n < 4; ++n) acc[m][n] = (f32x4){0.f, 0.f, 0.f, 0.f};

    const ushort_t* Wg = Wptr + (size_t)(n0 + (t >> 2)) * D_MODEL + (t & 3) * 8;
    ushort_t* WsW = Ws + w * 512;
    const float* Ag32 = Ain + (size_t)(m0 + (t >> 1)) * D_MODEL + (t & 1) * 16;

    for (int k0 = 0; k0 < D_MODEL; k0 += 32) {
        __syncthreads();
        {
            const float4* ap = (const float4*)(Ag32 + k0);
            float4 f0 = ap[0], f1 = ap[1], f2 = ap[2], f3 = ap[3];
            uint4 u0, u1;
            u0.x = cvt_pk_bf16(f0.x, f0.y); u0.y = cvt_pk_bf16(f0.z, f0.w);
            u0.z = cvt_pk_bf16(f1.x, f1.y); u0.w = cvt_pk_bf16(f1.z, f1.w);
            u1.x = cvt_pk_bf16(f2.x, f2.y); u1.y = cvt_pk_bf16(f2.z, f2.w);
            u1.z = cvt_pk_bf16(f3.x, f3.y); u1.w = cvt_pk_bf16(f3.z, f3.w);
            uint4* dst = (uint4*)&As[(t >> 1) * 32 + (t & 1) * 16];
            dst[0] = u0; dst[1] = u1;
        }
        gload16(Wg + k0, WsW);
        gload16(Wg + (size_t)64 * D_MODEL + k0, WsW + 2048);
        __syncthreads();

        s16x8 af[4], bfr[4];
#pragma unroll
        for (int m = 0; m < 4; ++m)
            af[m] = *(const s16x8*)&As[(wr * 64 + m * 16 + l15) * 32 + l4 * 8];
#pragma unroll
        for (int n = 0; n < 4; ++n)
            bfr[n] = *(const s16x8*)&Ws[(wc * 64 + n * 16 + l15) * 32 + l4 * 8];
#pragma unroll
        for (int m = 0; m < 4; ++m)
#pragma unroll
            for (int n = 0; n < 4; ++n)
                acc[m][n] = __builtin_amdgcn_mfma_f32_16x16x32_bf16(af[m], bfr[n], acc[m][n], 0, 0, 0);
    }

    if (z == 2) {   // transposed per-head epilogue -> Vtb[b][h][d][s], 2 halves
        ushort_t* Ct = (ushort_t*)pool;   // [64][136]
        const int h0 = n0 >> 6;           // first of 2 heads
        const int bb = m0 >> 11;
        const int s0 = m0 & (SEQ - 1);
#pragma unroll
        for (int hh = 0; hh < 2; ++hh) {
            __syncthreads();
            if (wc == hh) {
#pragma unroll
                for (int n = 0; n < 4; ++n) {
                    const int nl = n * 16 + l15;
                    const float bv = bias[n0 + hh * 64 + nl];
#pragma unroll
                    for (int m = 0; m < 4; ++m) {
                        const int ml = wr * 64 + m * 16 + l4 * 4;
#pragma unroll
                        for (int r = 0; r < 4; ++r)
                            Ct[nl * 136 + ml + r] = f2bf(acc[m][n][r] + bv);
                    }
                }
            }
            __syncthreads();
            const int dl = t >> 2;
            ushort_t* dst = Vtb + (((size_t)bb * NHEAD + h0 + hh) * DKH + dl) * SEQ + s0;
#pragma unroll
            for (int c = 0; c < 4; ++c) {
                int chk = (t & 3) + c * 4;
                *(uint4*)&dst[chk * 8] = *(const uint4*)&Ct[dl * 136 + chk * 8];
            }
        }
    } else {
        ushort_t* Cout = z == 0 ? Qb : Kb;
#pragma unroll
        for (int n = 0; n < 4; ++n) {
            const int col = n0 + wc * 64 + n * 16 + l15;
            const float bv = bias[col];
#pragma unroll
            for (int m = 0; m < 4; ++m) {
                const int row = m0 + wr * 64 + m * 16 + l4 * 4;
#pragma unroll
                for (int r = 0; r < 4; ++r)
                    Cout[(size_t)(row + r) * D_MODEL + col] = f2bf(acc[m][n][r] + bv);
            }
        }
    }
}

// ---------------------------------------------------------------------------
// Output projection GEMM: C[TOK][D] fp32 = Ctx_bf16 @ (Wohi + Wolo)^T + bias.
// BM=128 BN=64 BK=32, 256 thr, global_load_lds staging + chunked XCD swizzle.
// ---------------------------------------------------------------------------
__global__ __launch_bounds__(256) void gemm_out(
    const ushort_t* __restrict__ Ain, const ushort_t* __restrict__ Wptr,
    const ushort_t* __restrict__ W2ptr, const float* __restrict__ bias,
    float* __restrict__ Cout)
{
    __shared__ ushort_t As[128 * 32];
    __shared__ ushort_t Ws[64 * 32];
    __shared__ ushort_t Ws2[64 * 32];

    // chunked XCD swizzle over the 16x32 grid (512 blocks, 64/XCD)
    const int hwid = blockIdx.x + 16 * blockIdx.y;
    const int work = (hwid & 7) * 64 + (hwid >> 3);
    const int m0 = (work >> 4) * 128;
    const int n0 = (work & 15) * 64;

    const int t = threadIdx.x;
    const int w = t >> 6, lane = t & 63, l15 = lane & 15, l4 = lane >> 4;
    const int wr = w >> 1, wc = w & 1;

    f32x4 acc[4][2];
#pragma unroll
    for (int m = 0; m < 4; ++m)
#pragma unroll
        for (int n = 0; n < 2; ++n) acc[m][n] = (f32x4){0.f, 0.f, 0.f, 0.f};

    const ushort_t* Ag  = Ain   + (size_t)(m0 + (t >> 2)) * D_MODEL + (t & 3) * 8;
    const ushort_t* Wg  = Wptr  + (size_t)(n0 + (t >> 2)) * D_MODEL + (t & 3) * 8;
    const ushort_t* W2g = W2ptr + (size_t)(n0 + (t >> 2)) * D_MODEL + (t & 3) * 8;
    ushort_t* AsW = As + w * 512;
    ushort_t* WsW = Ws + w * 512;
    ushort_t* Ws2W = Ws2 + w * 512;

    for (int k0 = 0; k0 < D_MODEL; k0 += 32) {
        __syncthreads();
        gload16(Ag + k0, AsW);
        gload16(Ag + (size_t)64 * D_MODEL + k0, AsW + 2048);
        gload16(Wg + k0, WsW);
        gload16(W2g + k0, Ws2W);
        __syncthreads();

        s16x8 af[4], bfr[2], bfr2[2];
#pragma unroll
        for (int m = 0; m < 4; ++m)
            af[m] = *(const s16x8*)&As[(wr * 64 + m * 16 + l15) * 32 + l4 * 8];
#pragma unroll
        for (int n = 0; n < 2; ++n) {
            bfr[n]  = *(const s16x8*)&Ws[(wc * 32 + n * 16 + l15) * 32 + l4 * 8];
            bfr2[n] = *(const s16x8*)&Ws2[(wc * 32 + n * 16 + l15) * 32 + l4 * 8];
        }
#pragma unroll
        for (int m = 0; m < 4; ++m)
#pragma unroll
            for (int n = 0; n < 2; ++n) {
                acc[m][n] = __builtin_amdgcn_mfma_f32_16x16x32_bf16(af[m], bfr[n],  acc[m][n], 0, 0, 0);
                acc[m][n] = __builtin_amdgcn_mfma_f32_16x16x32_bf16(af[m], bfr2[n], acc[m][n], 0, 0, 0);
            }
    }

#pragma unroll
    for (int n = 0; n < 2; ++n) {
        const int col = n0 + wc * 32 + n * 16 + l15;
        const float bv = bias[col];
#pragma unroll
        for (int m = 0; m < 4; ++m) {
            const int row = m0 + wr * 64 + m * 16 + l4 * 4;
#pragma unroll
            for (int r = 0; r < 4; ++r)
                Cout[(size_t)(row + r) * D_MODEL + col] = acc[m][n][r] + bv;
        }
    }
}

// ---------------------------------------------------------------------------
// Flash attention (verified flash2, byte-identical to round 8): grid (bh, qt).
// ---------------------------------------------------------------------------
__global__ __launch_bounds__(256) void flash2(
    const ushort_t* __restrict__ Q, const ushort_t* __restrict__ K,
    const ushort_t* __restrict__ Vt, const float* __restrict__ mb,
    ushort_t* __restrict__ Ctx)
{
    __shared__ ushort_t Ks[64 * 72];
    __shared__ ushort_t Vs[64 * 72];
    __shared__ ushort_t Ps[64 * 72];

    const int t = threadIdx.x;
    const int w = t >> 6, lane = t & 63, l15 = lane & 15, l4 = lane >> 4;
    const int q0 = blockIdx.y * 64;
    const int bh = blockIdx.x, b = bh >> 4, h = bh & 15;

    s16x8 qf0, qf1;
    {
        const ushort_t* qp = Q + ((size_t)b * SEQ + q0 + w * 16 + l15) * D_MODEL + h * DKH + l4 * 8;
        qf0 = *(const s16x8*)qp;
        qf1 = *(const s16x8*)(qp + 32);
    }

    f32x4 oacc[4];
#pragma unroll
    for (int dt = 0; dt < 4; ++dt) oacc[dt] = (f32x4){0.f, 0.f, 0.f, 0.f};
    float lpart[4] = {0.f, 0.f, 0.f, 0.f};

    const int ch   = t & 7;
    const int row0 = t >> 3;
    const ushort_t* Kg = K  + ((size_t)b * SEQ) * D_MODEL + h * DKH + ch * 8;
    const ushort_t* Vg = Vt + ((size_t)bh * DKH) * SEQ + ch * 8;

    uint4 kr0 = *(const uint4*)&Kg[(size_t)row0 * D_MODEL];
    uint4 kr1 = *(const uint4*)&Kg[(size_t)(row0 + 32) * D_MODEL];
    uint4 vr0 = *(const uint4*)&Vg[(size_t)row0 * SEQ];
    uint4 vr1 = *(const uint4*)&Vg[(size_t)(row0 + 32) * SEQ];

    const float CSC = 0.18033688011112042f;   // 0.125 * log2(e)
    const float* mbp = mb + b * SEQ;

    for (int k0 = 0; k0 < SEQ; k0 += 64) {
        __syncthreads();
        *(uint4*)&Ks[row0 * 72 + ch * 8]        = kr0;
        *(uint4*)&Ks[(row0 + 32) * 72 + ch * 8] = kr1;
        *(uint4*)&Vs[row0 * 72 + ch * 8]        = vr0;
        *(uint4*)&Vs[(row0 + 32) * 72 + ch * 8] = vr1;
        __syncthreads();
        if (k0 + 64 < SEQ) {
            kr0 = *(const uint4*)&Kg[(size_t)(k0 + 64 + row0) * D_MODEL];
            kr1 = *(const uint4*)&Kg[(size_t)(k0 + 64 + row0 + 32) * D_MODEL];
            vr0 = *(const uint4*)&Vg[(size_t)row0 * SEQ + k0 + 64];
            vr1 = *(const uint4*)&Vg[(size_t)(row0 + 32) * SEQ + k0 + 64];
        }
        float mbv[4];
#pragma unroll
        for (int ct = 0; ct < 4; ++ct) mbv[ct] = mbp[k0 + ct * 16 + l15];

        f32x4 sacc[4];
#pragma unroll
        for (int ct = 0; ct < 4; ++ct) sacc[ct] = (f32x4){0.f, 0.f, 0.f, 0.f};
#pragma unroll
        for (int ct = 0; ct < 4; ++ct) {
            s16x8 b0 = *(const s16x8*)&Ks[(ct * 16 + l15) * 72 + l4 * 8];
            s16x8 b1 = *(const s16x8*)&Ks[(ct * 16 + l15) * 72 + 32 + l4 * 8];
            sacc[ct] = __builtin_amdgcn_mfma_f32_16x16x32_bf16(qf0, b0, sacc[ct], 0, 0, 0);
            sacc[ct] = __builtin_amdgcn_mfma_f32_16x16x32_bf16(qf1, b1, sacc[ct], 0, 0, 0);
        }

#pragma unroll
        for (int ct = 0; ct < 4; ++ct) {
            float p0 = __builtin_amdgcn_exp2f(fmaf(sacc[ct][0], CSC, mbv[ct]));
            float p1 = __builtin_amdgcn_exp2f(fmaf(sacc[ct][1], CSC, mbv[ct]));
            float p2 = __builtin_amdgcn_exp2f(fmaf(sacc[ct][2], CSC, mbv[ct]));
            float p3 = __builtin_amdgcn_exp2f(fmaf(sacc[ct][3], CSC, mbv[ct]));
            lpart[0] += p0; lpart[1] += p1; lpart[2] += p2; lpart[3] += p3;
            unsigned u01 = cvt_pk_bf16(p0, p1);
            unsigned u23 = cvt_pk_bf16(p2, p3);
            int base = (w * 16 + l4 * 4) * 72 + ct * 16 + l15;
            Ps[base]       = (ushort_t)u01;
            Ps[base + 72]  = (ushort_t)(u01 >> 16);
            Ps[base + 144] = (ushort_t)u23;
            Ps[base + 216] = (ushort_t)(u23 >> 16);
        }

#pragma unroll
        for (int ks = 0; ks < 2; ++ks) {
            s16x8 af = *(const s16x8*)&Ps[(w * 16 + l15) * 72 + ks * 32 + l4 * 8];
#pragma unroll
            for (int dt = 0; dt < 4; ++dt) {
                s16x8 bf = *(const s16x8*)&Vs[(dt * 16 + l15) * 72 + ks * 32 + l4 * 8];
                oacc[dt] = __builtin_amdgcn_mfma_f32_16x16x32_bf16(af, bf, oacc[dt], 0, 0, 0);
            }
        }
    }

#pragma unroll
    for (int r = 0; r < 4; ++r) {
        lpart[r] += __shfl_xor(lpart[r], 1);
        lpart[r] += __shfl_xor(lpart[r], 2);
        lpart[r] += __shfl_xor(lpart[r], 4);
        lpart[r] += __shfl_xor(lpart[r], 8);
    }
    const size_t obase = ((size_t)b * SEQ + q0 + w * 16 + l4 * 4) * D_MODEL + h * DKH + l15;
#pragma unroll
    for (int r = 0; r < 4; ++r) {
        float inv = 1.f / lpart[r];
#pragma unroll
        for (int dt = 0; dt < 4; ++dt)
            Ctx[obase + (size_t)r * D_MODEL + dt * 16] = f2bf(oacc[dt][r] * inv);
    }
}

extern "C" void kernel_launch(void* const* d_in, const int* in_sizes, int n_in,
                              void* d_out, int out_size, void* d_ws, size_t ws_size,
                              hipStream_t stream) {
    const float* q    = (const float*)d_in[0];
    const float* k    = (const float*)d_in[1];
    const float* v    = (const float*)d_in[2];
    const int*   mask = (const int*)  d_in[3];
    const float* Wq   = (const float*)d_in[4];
    const float* bq   = (const float*)d_in[5];
    const float* Wk   = (const float*)d_in[6];
    const float* bk   = (const float*)d_in[7];
    const float* Wv   = (const float*)d_in[8];
    const float* bv   = (const float*)d_in[9];
    const float* Wo   = (const float*)d_in[10];
    const float* bo   = (const float*)d_in[11];
    float* out = (float*)d_out;

    char* ws = (char*)d_ws;
    ushort_t* Wqb  = (ushort_t*)(ws);
    ushort_t* Wkb  = (ushort_t*)(ws + ( 2u << 20));
    ushort_t* Wvb  = (ushort_t*)(ws + ( 4u << 20));
    ushort_t* Wohi = (ushort_t*)(ws + ( 6u << 20));
    ushort_t* Wolo = (ushort_t*)(ws + ( 8u << 20));
    float*    mb   = (float*)   (ws + (10u << 20));
    ushort_t* Qb   = (ushort_t*)(ws + (12u << 20));
    ushort_t* Kb   = (ushort_t*)(ws + (20u << 20));
    ushort_t* Vtb  = (ushort_t*)(ws + (28u << 20));
    ushort_t* Ctx  = (ushort_t*)(ws + (36u << 20));

    convert_w<<<1024, 256, 0, stream>>>(Wq, Wk, Wv, Wo, mask,
                                        Wqb, Wkb, Wvb, Wohi, Wolo, mb);

    dim3 qkvgrid(D_MODEL / 128, TOK / 128, 3);
    gemm_qkv<<<qkvgrid, 256, 0, stream>>>(q, k, v, Wqb, Wkb, Wvb,
                                          bq, bk, bv, Qb, Kb, Vtb);

    dim3 agrid(BATCH * NHEAD, SEQ / 64);   // x=bh -> XCD-local K/V reuse
    flash2<<<agrid, 256, 0, stream>>>(Qb, Kb, Vtb, mb, Ctx);

    dim3 ogrid(D_MODEL / 64, TOK / 128);
    gemm_out<<<ogrid, 256, 0, stream>>>(Ctx, Wohi, Wolo, bo, out);
}

// Round 10
// 177.396 us; speedup vs baseline: 1.6292x; 1.0111x over previous
//
#include <hip/hip_runtime.h>
#include <math.h>

#define D_MODEL 1024
#define NHEAD   16
#define DKH     64
#define SEQ     2048
#define BATCH   2
#define TOK     (BATCH*SEQ)   // 4096

typedef short s16x8 __attribute__((ext_vector_type(8)));
typedef float f32x4 __attribute__((ext_vector_type(4)));
typedef unsigned short ushort_t;

__device__ inline unsigned short f2bf(float f) {
    union { float f; unsigned u; } v; v.f = f;
    unsigned r = v.u + 0x7FFFu + ((v.u >> 16) & 1u);   // RNE
    return (unsigned short)(r >> 16);
}
__device__ inline float bf2f(ushort_t h) {
    union { unsigned u; float f; } v; v.u = (unsigned)h << 16;
    return v.f;
}
__device__ inline unsigned cvt_pk_bf16(float a, float b) {  // low16=bf16(a), high16=bf16(b)
    unsigned r;
    asm("v_cvt_pk_bf16_f32 %0, %1, %2" : "=v"(r) : "v"(a), "v"(b));
    return r;
}
__device__ inline void gload16(const void* g, void* l) {
    __builtin_amdgcn_global_load_lds(
        (const __attribute__((address_space(1))) void*)g,
        (__attribute__((address_space(3))) void*)l, 16, 0, 0);
}

// ---------------------------------------------------------------------------
// Weights fp32->bf16 (Wo as hi+lo split) + mask -> float bias (-1e9 / 0).
// ---------------------------------------------------------------------------
__global__ __launch_bounds__(256) void convert_w(
    const float* __restrict__ Wq, const float* __restrict__ Wk,
    const float* __restrict__ Wv, const float* __restrict__ Wo,
    const int* __restrict__ mask,
    ushort_t* __restrict__ Wqb, ushort_t* __restrict__ Wkb,
    ushort_t* __restrict__ Wvb, ushort_t* __restrict__ Wohi,
    ushort_t* __restrict__ Wolo, float* __restrict__ mb)
{
    const int W4 = D_MODEL * D_MODEL / 4;   // 262144
    const int total = 4 * W4 + TOK / 4;
    for (int u = blockIdx.x * 256 + threadIdx.x; u < total; u += gridDim.x * 256) {
        if (u < 3 * W4) {
            int which = u / W4, off = u - which * W4;
            const float* src = which == 0 ? Wq : which == 1 ? Wk : Wv;
            ushort_t*    dst = which == 0 ? Wqb : which == 1 ? Wkb : Wvb;
            float4 f = ((const float4*)src)[off];
            uint2 o;
            o.x = cvt_pk_bf16(f.x, f.y);
            o.y = cvt_pk_bf16(f.z, f.w);
            ((uint2*)dst)[off] = o;
        } else if (u < 4 * W4) {
            int off = u - 3 * W4;
            float4 f = ((const float4*)Wo)[off];
            ushort_t h0 = f2bf(f.x), h1 = f2bf(f.y), h2 = f2bf(f.z), h3 = f2bf(f.w);
            uint2 hw;
            hw.x = (unsigned)h0 | ((unsigned)h1 << 16);
            hw.y = (unsigned)h2 | ((unsigned)h3 << 16);
            ((uint2*)Wohi)[off] = hw;
            uint2 lw;
            lw.x = cvt_pk_bf16(f.x - bf2f(h0), f.y - bf2f(h1));
            lw.y = cvt_pk_bf16(f.z - bf2f(h2), f.w - bf2f(h3));
            ((uint2*)Wolo)[off] = lw;
        } else {
            int off = u - 4 * W4;
            int4 m = ((const int4*)mask)[off];
            float4 f;
            f.x = m.x ? 0.f : -1e9f;
            f.y = m.y ? 0.f : -1e9f;
            f.z = m.z ? 0.f : -1e9f;
            f.w = m.w ? 0.f : -1e9f;
            ((float4*)mb)[off] = f;
        }
    }
}

// ---------------------------------------------------------------------------
// Fused Q/K/V projection GEMM: blockIdx.z selects {q,k,v}.
// BM=128 BN=128 BK=32, 256 thr, wave-tile 64x64 (16 MFMA/K-step).
// Chunked XCD swizzle (round-9, kept: FETCH = ideal 49MB).
// NEW: A tile software-pipelined through registers (T14) — next K-step's
// fp32 loads issue right after the staging barrier, latency hides under
// the 64-MFMA compute phase; cvt+ds_write at next iteration top.
// ---------------------------------------------------------------------------
__global__ __launch_bounds__(256) void gemm_qkv(
    const float* __restrict__ qin, const float* __restrict__ kin,
    const float* __restrict__ vin,
    const ushort_t* __restrict__ Wqb, const ushort_t* __restrict__ Wkb,
    const ushort_t* __restrict__ Wvb,
    const float* __restrict__ bqp, const float* __restrict__ bkp,
    const float* __restrict__ bvp,
    ushort_t* __restrict__ Qb, ushort_t* __restrict__ Kb,
    ushort_t* __restrict__ Vtb)
{
    __shared__ __align__(16) char pool[64 * 136 * 2];   // >=16KB staging, 17KB epi
    ushort_t* As = (ushort_t*)pool;                     // [128][32]
    ushort_t* Ws = As + 128 * 32;                       // [128][32]

    const int z = blockIdx.z;
    const float*    Ain  = z == 0 ? qin : z == 1 ? kin : vin;
    const ushort_t* Wptr = z == 0 ? Wqb : z == 1 ? Wkb : Wvb;
    const float*    bias = z == 0 ? bqp : z == 1 ? bkp : bvp;

    // bijective chunked XCD swizzle over the 8x32 (x,y) grid
    const int hwid = blockIdx.x + 8 * blockIdx.y;       // 0..255, XCD = hwid%8
    const int work = (hwid & 7) * 32 + (hwid >> 3);
    const int m0 = (work >> 3) * 128;                   // y-tile
    const int n0 = (work & 7) * 128;                    // x-tile

    const int t = threadIdx.x;
    const int w = t >> 6, lane = t & 63, l15 = lane & 15, l4 = lane >> 4;
    const int wr = w >> 1, wc = w & 1;

    f32x4 acc[4][4];
#pragma unroll
    for (int m = 0; m < 4; ++m)
#pragma unroll
        for (int n = 0; n < 4; ++n) acc[m][n] = (f32x4){0.f, 0.f, 0.f, 0.f};

    const ushort_t* Wg = Wptr + (size_t)(n0 + (t >> 2)) * D_MODEL + (t & 3) * 8;
    ushort_t* WsW = Ws + w * 512;
    const float* Ag32 = Ain + (size_t)(m0 + (t >> 1)) * D_MODEL + (t & 1) * 16;

    // prologue: load first A tile into regs
    float4 ar0, ar1, ar2, ar3;
    {
        const float4* ap = (const float4*)Ag32;
        ar0 = ap[0]; ar1 = ap[1]; ar2 = ap[2]; ar3 = ap[3];
    }

    for (int k0 = 0; k0 < D_MODEL; k0 += 32) {
        __syncthreads();   // previous compute done reading LDS
        {
            uint4 u0, u1;
            u0.x = cvt_pk_bf16(ar0.x, ar0.y); u0.y = cvt_pk_bf16(ar0.z, ar0.w);
            u0.z = cvt_pk_bf16(ar1.x, ar1.y); u0.w = cvt_pk_bf16(ar1.z, ar1.w);
            u1.x = cvt_pk_bf16(ar2.x, ar2.y); u1.y = cvt_pk_bf16(ar2.z, ar2.w);
            u1.z = cvt_pk_bf16(ar3.x, ar3.y); u1.w = cvt_pk_bf16(ar3.z, ar3.w);
            uint4* dst = (uint4*)&As[(t >> 1) * 32 + (t & 1) * 16];
            dst[0] = u0; dst[1] = u1;
        }
        gload16(Wg + k0, WsW);
        gload16(Wg + (size_t)64 * D_MODEL + k0, WsW + 2048);
        __syncthreads();   // staging visible

        if (k0 + 32 < D_MODEL) {   // prefetch next A tile; hides under MFMA
            const float4* ap = (const float4*)(Ag32 + k0 + 32);
            ar0 = ap[0]; ar1 = ap[1]; ar2 = ap[2]; ar3 = ap[3];
        }

        s16x8 af[4], bfr[4];
#pragma unroll
        for (int m = 0; m < 4; ++m)
            af[m] = *(const s16x8*)&As[(wr * 64 + m * 16 + l15) * 32 + l4 * 8];
#pragma unroll
        for (int n = 0; n < 4; ++n)
            bfr[n] = *(const s16x8*)&Ws[(wc * 64 + n * 16 + l15) * 32 + l4 * 8];
#pragma unroll
        for (int m = 0; m < 4; ++m)
#pragma unroll
            for (int n = 0; n < 4; ++n)
                acc[m][n] = __builtin_amdgcn_mfma_f32_16x16x32_bf16(af[m], bfr[n], acc[m][n], 0, 0, 0);
    }

    if (z == 2) {   // transposed per-head epilogue -> Vtb[b][h][d][s], 2 halves
        ushort_t* Ct = (ushort_t*)pool;   // [64][136]
        const int h0 = n0 >> 6;           // first of 2 heads
        const int bb = m0 >> 11;
        const int s0 = m0 & (SEQ - 1);
#pragma unroll
        for (int hh = 0; hh < 2; ++hh) {
            __syncthreads();
            if (wc == hh) {
#pragma unroll
                for (int n = 0; n < 4; ++n) {
                    const int nl = n * 16 + l15;
                    const float bv = bias[n0 + hh * 64 + nl];
#pragma unroll
                    for (int m = 0; m < 4; ++m) {
                        const int ml = wr * 64 + m * 16 + l4 * 4;
#pragma unroll
                        for (int r = 0; r < 4; ++r)
                            Ct[nl * 136 + ml + r] = f2bf(acc[m][n][r] + bv);
                    }
                }
            }
            __syncthreads();
            const int dl = t >> 2;
            ushort_t* dst = Vtb + (((size_t)bb * NHEAD + h0 + hh) * DKH + dl) * SEQ + s0;
#pragma unroll
            for (int c = 0; c < 4; ++c) {
                int chk = (t & 3) + c * 4;
                *(uint4*)&dst[chk * 8] = *(const uint4*)&Ct[dl * 136 + chk * 8];
            }
        }
    } else {
        ushort_t* Cout = z == 0 ? Qb : Kb;
#pragma unroll
        for (int n = 0; n < 4; ++n) {
            const int col = n0 + wc * 64 + n * 16 + l15;
            const float bv = bias[col];
#pragma unroll
            for (int m = 0; m < 4; ++m) {
                const int row = m0 + wr * 64 + m * 16 + l4 * 4;
#pragma unroll
                for (int r = 0; r < 4; ++r)
                    Cout[(size_t)(row + r) * D_MODEL + col] = f2bf(acc[m][n][r] + bv);
            }
        }
    }
}

// ---------------------------------------------------------------------------
// Output projection GEMM: C[TOK][D] fp32 = Ctx_bf16 @ (Wohi + Wolo)^T + bias.
// BM=128 BN=64 BK=32, 256 thr, global_load_lds staging + chunked XCD swizzle.
// ---------------------------------------------------------------------------
__global__ __launch_bounds__(256) void gemm_out(
    const ushort_t* __restrict__ Ain, const ushort_t* __restrict__ Wptr,
    const ushort_t* __restrict__ W2ptr, const float* __restrict__ bias,
    float* __restrict__ Cout)
{
    __shared__ ushort_t As[128 * 32];
    __shared__ ushort_t Ws[64 * 32];
    __shared__ ushort_t Ws2[64 * 32];

    // chunked XCD swizzle over the 16x32 grid (512 blocks, 64/XCD)
    const int hwid = blockIdx.x + 16 * blockIdx.y;
    const int work = (hwid & 7) * 64 + (hwid >> 3);
    const int m0 = (work >> 4) * 128;
    const int n0 = (work & 15) * 64;

    const int t = threadIdx.x;
    const int w = t >> 6, lane = t & 63, l15 = lane & 15, l4 = lane >> 4;
    const int wr = w >> 1, wc = w & 1;

    f32x4 acc[4][2];
#pragma unroll
    for (int m = 0; m < 4; ++m)
#pragma unroll
        for (int n = 0; n < 2; ++n) acc[m][n] = (f32x4){0.f, 0.f, 0.f, 0.f};

    const ushort_t* Ag  = Ain   + (size_t)(m0 + (t >> 2)) * D_MODEL + (t & 3) * 8;
    const ushort_t* Wg  = Wptr  + (size_t)(n0 + (t >> 2)) * D_MODEL + (t & 3) * 8;
    const ushort_t* W2g = W2ptr + (size_t)(n0 + (t >> 2)) * D_MODEL + (t & 3) * 8;
    ushort_t* AsW = As + w * 512;
    ushort_t* WsW = Ws + w * 512;
    ushort_t* Ws2W = Ws2 + w * 512;

    for (int k0 = 0; k0 < D_MODEL; k0 += 32) {
        __syncthreads();
        gload16(Ag + k0, AsW);
        gload16(Ag + (size_t)64 * D_MODEL + k0, AsW + 2048);
        gload16(Wg + k0, WsW);
        gload16(W2g + k0, Ws2W);
        __syncthreads();

        s16x8 af[4], bfr[2], bfr2[2];
#pragma unroll
        for (int m = 0; m < 4; ++m)
            af[m] = *(const s16x8*)&As[(wr * 64 + m * 16 + l15) * 32 + l4 * 8];
#pragma unroll
        for (int n = 0; n < 2; ++n) {
            bfr[n]  = *(const s16x8*)&Ws[(wc * 32 + n * 16 + l15) * 32 + l4 * 8];
            bfr2[n] = *(const s16x8*)&Ws2[(wc * 32 + n * 16 + l15) * 32 + l4 * 8];
        }
#pragma unroll
        for (int m = 0; m < 4; ++m)
#pragma unroll
            for (int n = 0; n < 2; ++n) {
                acc[m][n] = __builtin_amdgcn_mfma_f32_16x16x32_bf16(af[m], bfr[n],  acc[m][n], 0, 0, 0);
                acc[m][n] = __builtin_amdgcn_mfma_f32_16x16x32_bf16(af[m], bfr2[n], acc[m][n], 0, 0, 0);
            }
    }

#pragma unroll
    for (int n = 0; n < 2; ++n) {
        const int col = n0 + wc * 32 + n * 16 + l15;
        const float bv = bias[col];
#pragma unroll
        for (int m = 0; m < 4; ++m) {
            const int row = m0 + wr * 64 + m * 16 + l4 * 4;
#pragma unroll
            for (int r = 0; r < 4; ++r)
                Cout[(size_t)(row + r) * D_MODEL + col] = acc[m][n][r] + bv;
        }
    }
}

// ---------------------------------------------------------------------------
// Flash attention (verified flash2, byte-identical to round 8): grid (bh, qt).
// ---------------------------------------------------------------------------
__global__ __launch_bounds__(256) void flash2(
    const ushort_t* __restrict__ Q, const ushort_t* __restrict__ K,
    const ushort_t* __restrict__ Vt, const float* __restrict__ mb,
    ushort_t* __restrict__ Ctx)
{
    __shared__ ushort_t Ks[64 * 72];
    __shared__ ushort_t Vs[64 * 72];
    __shared__ ushort_t Ps[64 * 72];

    const int t = threadIdx.x;
    const int w = t >> 6, lane = t & 63, l15 = lane & 15, l4 = lane >> 4;
    const int q0 = blockIdx.y * 64;
    const int bh = blockIdx.x, b = bh >> 4, h = bh & 15;

    s16x8 qf0, qf1;
    {
        const ushort_t* qp = Q + ((size_t)b * SEQ + q0 + w * 16 + l15) * D_MODEL + h * DKH + l4 * 8;
        qf0 = *(const s16x8*)qp;
        qf1 = *(const s16x8*)(qp + 32);
    }

    f32x4 oacc[4];
#pragma unroll
    for (int dt = 0; dt < 4; ++dt) oacc[dt] = (f32x4){0.f, 0.f, 0.f, 0.f};
    float lpart[4] = {0.f, 0.f, 0.f, 0.f};

    const int ch   = t & 7;
    const int row0 = t >> 3;
    const ushort_t* Kg = K  + ((size_t)b * SEQ) * D_MODEL + h * DKH + ch * 8;
    const ushort_t* Vg = Vt + ((size_t)bh * DKH) * SEQ + ch * 8;

    uint4 kr0 = *(const uint4*)&Kg[(size_t)row0 * D_MODEL];
    uint4 kr1 = *(const uint4*)&Kg[(size_t)(row0 + 32) * D_MODEL];
    uint4 vr0 = *(const uint4*)&Vg[(size_t)row0 * SEQ];
    uint4 vr1 = *(const uint4*)&Vg[(size_t)(row0 + 32) * SEQ];

    const float CSC = 0.18033688011112042f;   // 0.125 * log2(e)
    const float* mbp = mb + b * SEQ;

    for (int k0 = 0; k0 < SEQ; k0 += 64) {
        __syncthreads();
        *(uint4*)&Ks[row0 * 72 + ch * 8]        = kr0;
        *(uint4*)&Ks[(row0 + 32) * 72 + ch * 8] = kr1;
        *(uint4*)&Vs[row0 * 72 + ch * 8]        = vr0;
        *(uint4*)&Vs[(row0 + 32) * 72 + ch * 8] = vr1;
        __syncthreads();
        if (k0 + 64 < SEQ) {
            kr0 = *(const uint4*)&Kg[(size_t)(k0 + 64 + row0) * D_MODEL];
            kr1 = *(const uint4*)&Kg[(size_t)(k0 + 64 + row0 + 32) * D_MODEL];
            vr0 = *(const uint4*)&Vg[(size_t)row0 * SEQ + k0 + 64];
            vr1 = *(const uint4*)&Vg[(size_t)(row0 + 32) * SEQ + k0 + 64];
        }
        float mbv[4];
#pragma unroll
        for (int ct = 0; ct < 4; ++ct) mbv[ct] = mbp[k0 + ct * 16 + l15];

        f32x4 sacc[4];
#pragma unroll
        for (int ct = 0; ct < 4; ++ct) sacc[ct] = (f32x4){0.f, 0.f, 0.f, 0.f};
#pragma unroll
        for (int ct = 0; ct < 4; ++ct) {
            s16x8 b0 = *(const s16x8*)&Ks[(ct * 16 + l15) * 72 + l4 * 8];
            s16x8 b1 = *(const s16x8*)&Ks[(ct * 16 + l15) * 72 + 32 + l4 * 8];
            sacc[ct] = __builtin_amdgcn_mfma_f32_16x16x32_bf16(qf0, b0, sacc[ct], 0, 0, 0);
            sacc[ct] = __builtin_amdgcn_mfma_f32_16x16x32_bf16(qf1, b1, sacc[ct], 0, 0, 0);
        }

#pragma unroll
        for (int ct = 0; ct < 4; ++ct) {
            float p0 = __builtin_amdgcn_exp2f(fmaf(sacc[ct][0], CSC, mbv[ct]));
            float p1 = __builtin_amdgcn_exp2f(fmaf(sacc[ct][1], CSC, mbv[ct]));
            float p2 = __builtin_amdgcn_exp2f(fmaf(sacc[ct][2], CSC, mbv[ct]));
            float p3 = __builtin_amdgcn_exp2f(fmaf(sacc[ct][3], CSC, mbv[ct]));
            lpart[0] += p0; lpart[1] += p1; lpart[2] += p2; lpart[3] += p3;
            unsigned u01 = cvt_pk_bf16(p0, p1);
            unsigned u23 = cvt_pk_bf16(p2, p3);
            int base = (w * 16 + l4 * 4) * 72 + ct * 16 + l15;
            Ps[base]       = (ushort_t)u01;
            Ps[base + 72]  = (ushort_t)(u01 >> 16);
            Ps[base + 144] = (ushort_t)u23;
            Ps[base + 216] = (ushort_t)(u23 >> 16);
        }

#pragma unroll
        for (int ks = 0; ks < 2; ++ks) {
            s16x8 af = *(const s16x8*)&Ps[(w * 16 + l15) * 72 + ks * 32 + l4 * 8];
#pragma unroll
            for (int dt = 0; dt < 4; ++dt) {
                s16x8 bf = *(const s16x8*)&Vs[(dt * 16 + l15) * 72 + ks * 32 + l4 * 8];
                oacc[dt] = __builtin_amdgcn_mfma_f32_16x16x32_bf16(af, bf, oacc[dt], 0, 0, 0);
            }
        }
    }

#pragma unroll
    for (int r = 0; r < 4; ++r) {
        lpart[r] += __shfl_xor(lpart[r], 1);
        lpart[r] += __shfl_xor(lpart[r], 2);
        lpart[r] += __shfl_xor(lpart[r], 4);
        lpart[r] += __shfl_xor(lpart[r], 8);
    }
    const size_t obase = ((size_t)b * SEQ + q0 + w * 16 + l4 * 4) * D_MODEL + h * DKH + l15;
#pragma unroll
    for (int r = 0; r < 4; ++r) {
        float inv = 1.f / lpart[r];
#pragma unroll
        for (int dt = 0; dt < 4; ++dt)
            Ctx[obase + (size_t)r * D_MODEL + dt * 16] = f2bf(oacc[dt][r] * inv);
    }
}

extern "C" void kernel_launch(void* const* d_in, const int* in_sizes, int n_in,
                              void* d_out, int out_size, void* d_ws, size_t ws_size,
                              hipStream_t stream) {
    const float* q    = (const float*)d_in[0];
    const float* k    = (const float*)d_in[1];
    const float* v    = (const float*)d_in[2];
    const int*   mask = (const int*)  d_in[3];
    const float* Wq   = (const float*)d_in[4];
    const float* bq   = (const float*)d_in[5];
    const float* Wk   = (const float*)d_in[6];
    const float* bk   = (const float*)d_in[7];
    const float* Wv   = (const float*)d_in[8];
    const float* bv   = (const float*)d_in[9];
    const float* Wo   = (const float*)d_in[10];
    const float* bo   = (const float*)d_in[11];
    float* out = (float*)d_out;

    char* ws = (char*)d_ws;
    ushort_t* Wqb  = (ushort_t*)(ws);
    ushort_t* Wkb  = (ushort_t*)(ws + ( 2u << 20));
    ushort_t* Wvb  = (ushort_t*)(ws + ( 4u << 20));
    ushort_t* Wohi = (ushort_t*)(ws + ( 6u << 20));
    ushort_t* Wolo = (ushort_t*)(ws + ( 8u << 20));
    float*    mb   = (float*)   (ws + (10u << 20));
    ushort_t* Qb   = (ushort_t*)(ws + (12u << 20));
    ushort_t* Kb   = (ushort_t*)(ws + (20u << 20));
    ushort_t* Vtb  = (ushort_t*)(ws + (28u << 20));
    ushort_t* Ctx  = (ushort_t*)(ws + (36u << 20));

    convert_w<<<1024, 256, 0, stream>>>(Wq, Wk, Wv, Wo, mask,
                                        Wqb, Wkb, Wvb, Wohi, Wolo, mb);

    dim3 qkvgrid(D_MODEL / 128, TOK / 128, 3);
    gemm_qkv<<<qkvgrid, 256, 0, stream>>>(q, k, v, Wqb, Wkb, Wvb,
                                          bq, bk, bv, Qb, Kb, Vtb);

    dim3 agrid(BATCH * NHEAD, SEQ / 64);   // x=bh -> XCD-local K/V reuse
    flash2<<<agrid, 256, 0, stream>>>(Qb, Kb, Vtb, mb, Ctx);

    dim3 ogrid(D_MODEL / 64, TOK / 128);
    gemm_out<<<ogrid, 256, 0, stream>>>(Ctx, Wohi, Wolo, bo, out);
}

// Round 11
// 158.182 us; speedup vs baseline: 1.8271x; 1.1215x over previous
//
#include <hip/hip_runtime.h>
#include <math.h>

#define D_MODEL 1024
#define NHEAD   16
#define DKH     64
#define SEQ     2048
#define BATCH   2
#define TOK     (BATCH*SEQ)   // 4096

typedef short s16x8 __attribute__((ext_vector_type(8)));
typedef float f32x4 __attribute__((ext_vector_type(4)));
typedef unsigned short ushort_t;

__device__ inline unsigned short f2bf(float f) {
    union { float f; unsigned u; } v; v.f = f;
    unsigned r = v.u + 0x7FFFu + ((v.u >> 16) & 1u);   // RNE
    return (unsigned short)(r >> 16);
}
__device__ inline float bf2f(ushort_t h) {
    union { unsigned u; float f; } v; v.u = (unsigned)h << 16;
    return v.f;
}
__device__ inline unsigned cvt_pk_bf16(float a, float b) {  // low16=bf16(a), high16=bf16(b)
    unsigned r;
    asm("v_cvt_pk_bf16_f32 %0, %1, %2" : "=v"(r) : "v"(a), "v"(b));
    return r;
}
__device__ inline void gload16(const void* g, void* l) {
    __builtin_amdgcn_global_load_lds(
        (const __attribute__((address_space(1))) void*)g,
        (__attribute__((address_space(3))) void*)l, 16, 0, 0);
}

// ---------------------------------------------------------------------------
// fp32->bf16: q,k,v and Wq,Wk,Wv plain; Wo as hi+lo split; mask -> float bias.
// ---------------------------------------------------------------------------
__global__ __launch_bounds__(256) void convert_all(
    const float* __restrict__ q, const float* __restrict__ k,
    const float* __restrict__ v,
    const float* __restrict__ Wq, const float* __restrict__ Wk,
    const float* __restrict__ Wv, const float* __restrict__ Wo,
    const int* __restrict__ mask,
    ushort_t* __restrict__ qb, ushort_t* __restrict__ kb,
    ushort_t* __restrict__ vb,
    ushort_t* __restrict__ Wqb, ushort_t* __restrict__ Wkb,
    ushort_t* __restrict__ Wvb, ushort_t* __restrict__ Wohi,
    ushort_t* __restrict__ Wolo, float* __restrict__ mb)
{
    const int ACT4 = TOK * D_MODEL / 4;       // 1048576
    const int W4   = D_MODEL * D_MODEL / 4;   // 262144
    const int total = 3 * ACT4 + 4 * W4 + TOK / 4;
    for (int u = blockIdx.x * 256 + threadIdx.x; u < total; u += gridDim.x * 256) {
        if (u < 3 * ACT4) {
            int which = u / ACT4, off = u - which * ACT4;
            const float* src = which == 0 ? q : which == 1 ? k : v;
            ushort_t*    dst = which == 0 ? qb : which == 1 ? kb : vb;
            float4 f = ((const float4*)src)[off];
            uint2 o;
            o.x = cvt_pk_bf16(f.x, f.y);
            o.y = cvt_pk_bf16(f.z, f.w);
            ((uint2*)dst)[off] = o;
        } else if (u < 3 * ACT4 + 3 * W4) {
            int uu = u - 3 * ACT4;
            int which = uu / W4, off = uu - which * W4;
            const float* src = which == 0 ? Wq : which == 1 ? Wk : Wv;
            ushort_t*    dst = which == 0 ? Wqb : which == 1 ? Wkb : Wvb;
            float4 f = ((const float4*)src)[off];
            uint2 o;
            o.x = cvt_pk_bf16(f.x, f.y);
            o.y = cvt_pk_bf16(f.z, f.w);
            ((uint2*)dst)[off] = o;
        } else if (u < 3 * ACT4 + 4 * W4) {
            int off = u - (3 * ACT4 + 3 * W4);
            float4 f = ((const float4*)Wo)[off];
            ushort_t h0 = f2bf(f.x), h1 = f2bf(f.y), h2 = f2bf(f.z), h3 = f2bf(f.w);
            uint2 hw;
            hw.x = (unsigned)h0 | ((unsigned)h1 << 16);
            hw.y = (unsigned)h2 | ((unsigned)h3 << 16);
            ((uint2*)Wohi)[off] = hw;
            uint2 lw;
            lw.x = cvt_pk_bf16(f.x - bf2f(h0), f.y - bf2f(h1));
            lw.y = cvt_pk_bf16(f.z - bf2f(h2), f.w - bf2f(h3));
            ((uint2*)Wolo)[off] = lw;
        } else {
            int off = u - (3 * ACT4 + 4 * W4);
            int4 m = ((const int4*)mask)[off];
            float4 f;
            f.x = m.x ? 0.f : -1e9f;
            f.y = m.y ? 0.f : -1e9f;
            f.z = m.z ? 0.f : -1e9f;
            f.w = m.w ? 0.f : -1e9f;
            ((float4*)mb)[off] = f;
        }
    }
}

// ---------------------------------------------------------------------------
// Fused Q/K/V projection GEMM, pure bf16 (m97 structure): blockIdx.z = {q,k,v}.
// BM=128 BN=128 BK=32, 256 thr, wave-tile 64x64, ALL staging via
// global_load_lds (async, no VGPR round-trip, lean register budget).
// Chunked XCD swizzle kept (round-9: FETCH = ideal).
// z<2 -> row-major bf16; z==2 -> per-head transposed [b][h][d][s].
// ---------------------------------------------------------------------------
__global__ __launch_bounds__(256) void gemm_qkv(
    const ushort_t* __restrict__ qb, const ushort_t* __restrict__ kb,
    const ushort_t* __restrict__ vb,
    const ushort_t* __restrict__ Wqb, const ushort_t* __restrict__ Wkb,
    const ushort_t* __restrict__ Wvb,
    const float* __restrict__ bqp, const float* __restrict__ bkp,
    const float* __restrict__ bvp,
    ushort_t* __restrict__ Qb, ushort_t* __restrict__ Kb,
    ushort_t* __restrict__ Vtb)
{
    __shared__ __align__(16) char pool[64 * 136 * 2];   // 16KB staging / 17KB epi
    ushort_t* As = (ushort_t*)pool;                     // [128][32]
    ushort_t* Ws = As + 128 * 32;                       // [128][32]

    const int z = blockIdx.z;
    const ushort_t* Ain  = z == 0 ? qb : z == 1 ? kb : vb;
    const ushort_t* Wptr = z == 0 ? Wqb : z == 1 ? Wkb : Wvb;
    const float*    bias = z == 0 ? bqp : z == 1 ? bkp : bvp;

    // bijective chunked XCD swizzle over the 8x32 (x,y) grid
    const int hwid = blockIdx.x + 8 * blockIdx.y;       // 0..255, XCD = hwid%8
    const int work = (hwid & 7) * 32 + (hwid >> 3);
    const int m0 = (work >> 3) * 128;
    const int n0 = (work & 7) * 128;

    const int t = threadIdx.x;
    const int w = t >> 6, lane = t & 63, l15 = lane & 15, l4 = lane >> 4;
    const int wr = w >> 1, wc = w & 1;

    f32x4 acc[4][4];
#pragma unroll
    for (int m = 0; m < 4; ++m)
#pragma unroll
        for (int n = 0; n < 4; ++n) acc[m][n] = (f32x4){0.f, 0.f, 0.f, 0.f};

    const ushort_t* Ag = Ain  + (size_t)(m0 + (t >> 2)) * D_MODEL + (t & 3) * 8;
    const ushort_t* Wg = Wptr + (size_t)(n0 + (t >> 2)) * D_MODEL + (t & 3) * 8;
    ushort_t* AsW = As + w * 512;
    ushort_t* WsW = Ws + w * 512;

    for (int k0 = 0; k0 < D_MODEL; k0 += 32) {
        __syncthreads();
        gload16(Ag + k0, AsW);
        gload16(Ag + (size_t)64 * D_MODEL + k0, AsW + 2048);
        gload16(Wg + k0, WsW);
        gload16(Wg + (size_t)64 * D_MODEL + k0, WsW + 2048);
        __syncthreads();

        s16x8 af[4], bfr[4];
#pragma unroll
        for (int m = 0; m < 4; ++m)
            af[m] = *(const s16x8*)&As[(wr * 64 + m * 16 + l15) * 32 + l4 * 8];
#pragma unroll
        for (int n = 0; n < 4; ++n)
            bfr[n] = *(const s16x8*)&Ws[(wc * 64 + n * 16 + l15) * 32 + l4 * 8];
#pragma unroll
        for (int m = 0; m < 4; ++m)
#pragma unroll
            for (int n = 0; n < 4; ++n)
                acc[m][n] = __builtin_amdgcn_mfma_f32_16x16x32_bf16(af[m], bfr[n], acc[m][n], 0, 0, 0);
    }

    if (z == 2) {   // transposed per-head epilogue -> Vtb[b][h][d][s], 2 halves
        ushort_t* Ct = (ushort_t*)pool;   // [64][136]
        const int h0 = n0 >> 6;
        const int bb = m0 >> 11;
        const int s0 = m0 & (SEQ - 1);
#pragma unroll
        for (int hh = 0; hh < 2; ++hh) {
            __syncthreads();
            if (wc == hh) {
#pragma unroll
                for (int n = 0; n < 4; ++n) {
                    const int nl = n * 16 + l15;
                    const float bv = bias[n0 + hh * 64 + nl];
#pragma unroll
                    for (int m = 0; m < 4; ++m) {
                        const int ml = wr * 64 + m * 16 + l4 * 4;
#pragma unroll
                        for (int r = 0; r < 4; ++r)
                            Ct[nl * 136 + ml + r] = f2bf(acc[m][n][r] + bv);
                    }
                }
            }
            __syncthreads();
            const int dl = t >> 2;
            ushort_t* dst = Vtb + (((size_t)bb * NHEAD + h0 + hh) * DKH + dl) * SEQ + s0;
#pragma unroll
            for (int c = 0; c < 4; ++c) {
                int chk = (t & 3) + c * 4;
                *(uint4*)&dst[chk * 8] = *(const uint4*)&Ct[dl * 136 + chk * 8];
            }
        }
    } else {
        ushort_t* Cout = z == 0 ? Qb : Kb;
#pragma unroll
        for (int n = 0; n < 4; ++n) {
            const int col = n0 + wc * 64 + n * 16 + l15;
            const float bv = bias[col];
#pragma unroll
            for (int m = 0; m < 4; ++m) {
                const int row = m0 + wr * 64 + m * 16 + l4 * 4;
#pragma unroll
                for (int r = 0; r < 4; ++r)
                    Cout[(size_t)(row + r) * D_MODEL + col] = f2bf(acc[m][n][r] + bv);
            }
        }
    }
}

// ---------------------------------------------------------------------------
// Output projection GEMM: C[TOK][D] fp32 = Ctx_bf16 @ (Wohi + Wolo)^T + bias.
// BM=128 BN=64 BK=32, 256 thr, global_load_lds staging + chunked XCD swizzle.
// ---------------------------------------------------------------------------
__global__ __launch_bounds__(256) void gemm_out(
    const ushort_t* __restrict__ Ain, const ushort_t* __restrict__ Wptr,
    const ushort_t* __restrict__ W2ptr, const float* __restrict__ bias,
    float* __restrict__ Cout)
{
    __shared__ ushort_t As[128 * 32];
    __shared__ ushort_t Ws[64 * 32];
    __shared__ ushort_t Ws2[64 * 32];

    // chunked XCD swizzle over the 16x32 grid (512 blocks, 64/XCD)
    const int hwid = blockIdx.x + 16 * blockIdx.y;
    const int work = (hwid & 7) * 64 + (hwid >> 3);
    const int m0 = (work >> 4) * 128;
    const int n0 = (work & 15) * 64;

    const int t = threadIdx.x;
    const int w = t >> 6, lane = t & 63, l15 = lane & 15, l4 = lane >> 4;
    const int wr = w >> 1, wc = w & 1;

    f32x4 acc[4][2];
#pragma unroll
    for (int m = 0; m < 4; ++m)
#pragma unroll
        for (int n = 0; n < 2; ++n) acc[m][n] = (f32x4){0.f, 0.f, 0.f, 0.f};

    const ushort_t* Ag  = Ain   + (size_t)(m0 + (t >> 2)) * D_MODEL + (t & 3) * 8;
    const ushort_t* Wg  = Wptr  + (size_t)(n0 + (t >> 2)) * D_MODEL + (t & 3) * 8;
    const ushort_t* W2g = W2ptr + (size_t)(n0 + (t >> 2)) * D_MODEL + (t & 3) * 8;
    ushort_t* AsW = As + w * 512;
    ushort_t* WsW = Ws + w * 512;
    ushort_t* Ws2W = Ws2 + w * 512;

    for (int k0 = 0; k0 < D_MODEL; k0 += 32) {
        __syncthreads();
        gload16(Ag + k0, AsW);
        gload16(Ag + (size_t)64 * D_MODEL + k0, AsW + 2048);
        gload16(Wg + k0, WsW);
        gload16(W2g + k0, Ws2W);
        __syncthreads();

        s16x8 af[4], bfr[2], bfr2[2];
#pragma unroll
        for (int m = 0; m < 4; ++m)
            af[m] = *(const s16x8*)&As[(wr * 64 + m * 16 + l15) * 32 + l4 * 8];
#pragma unroll
        for (int n = 0; n < 2; ++n) {
            bfr[n]  = *(const s16x8*)&Ws[(wc * 32 + n * 16 + l15) * 32 + l4 * 8];
            bfr2[n] = *(const s16x8*)&Ws2[(wc * 32 + n * 16 + l15) * 32 + l4 * 8];
        }
#pragma unroll
        for (int m = 0; m < 4; ++m)
#pragma unroll
            for (int n = 0; n < 2; ++n) {
                acc[m][n] = __builtin_amdgcn_mfma_f32_16x16x32_bf16(af[m], bfr[n],  acc[m][n], 0, 0, 0);
                acc[m][n] = __builtin_amdgcn_mfma_f32_16x16x32_bf16(af[m], bfr2[n], acc[m][n], 0, 0, 0);
            }
    }

#pragma unroll
    for (int n = 0; n < 2; ++n) {
        const int col = n0 + wc * 32 + n * 16 + l15;
        const float bv = bias[col];
#pragma unroll
        for (int m = 0; m < 4; ++m) {
            const int row = m0 + wr * 64 + m * 16 + l4 * 4;
#pragma unroll
            for (int r = 0; r < 4; ++r)
                Cout[(size_t)(row + r) * D_MODEL + col] = acc[m][n][r] + bv;
        }
    }
}

// ---------------------------------------------------------------------------
// Flash attention (verified flash2, byte-identical to round 8): grid (bh, qt).
// ---------------------------------------------------------------------------
__global__ __launch_bounds__(256) void flash2(
    const ushort_t* __restrict__ Q, const ushort_t* __restrict__ K,
    const ushort_t* __restrict__ Vt, const float* __restrict__ mb,
    ushort_t* __restrict__ Ctx)
{
    __shared__ ushort_t Ks[64 * 72];
    __shared__ ushort_t Vs[64 * 72];
    __shared__ ushort_t Ps[64 * 72];

    const int t = threadIdx.x;
    const int w = t >> 6, lane = t & 63, l15 = lane & 15, l4 = lane >> 4;
    const int q0 = blockIdx.y * 64;
    const int bh = blockIdx.x, b = bh >> 4, h = bh & 15;

    s16x8 qf0, qf1;
    {
        const ushort_t* qp = Q + ((size_t)b * SEQ + q0 + w * 16 + l15) * D_MODEL + h * DKH + l4 * 8;
        qf0 = *(const s16x8*)qp;
        qf1 = *(const s16x8*)(qp + 32);
    }

    f32x4 oacc[4];
#pragma unroll
    for (int dt = 0; dt < 4; ++dt) oacc[dt] = (f32x4){0.f, 0.f, 0.f, 0.f};
    float lpart[4] = {0.f, 0.f, 0.f, 0.f};

    const int ch   = t & 7;
    const int row0 = t >> 3;
    const ushort_t* Kg = K  + ((size_t)b * SEQ) * D_MODEL + h * DKH + ch * 8;
    const ushort_t* Vg = Vt + ((size_t)bh * DKH) * SEQ + ch * 8;

    uint4 kr0 = *(const uint4*)&Kg[(size_t)row0 * D_MODEL];
    uint4 kr1 = *(const uint4*)&Kg[(size_t)(row0 + 32) * D_MODEL];
    uint4 vr0 = *(const uint4*)&Vg[(size_t)row0 * SEQ];
    uint4 vr1 = *(const uint4*)&Vg[(size_t)(row0 + 32) * SEQ];

    const float CSC = 0.18033688011112042f;   // 0.125 * log2(e)
    const float* mbp = mb + b * SEQ;

    for (int k0 = 0; k0 < SEQ; k0 += 64) {
        __syncthreads();
        *(uint4*)&Ks[row0 * 72 + ch * 8]        = kr0;
        *(uint4*)&Ks[(row0 + 32) * 72 + ch * 8] = kr1;
        *(uint4*)&Vs[row0 * 72 + ch * 8]        = vr0;
        *(uint4*)&Vs[(row0 + 32) * 72 + ch * 8] = vr1;
        __syncthreads();
        if (k0 + 64 < SEQ) {
            kr0 = *(const uint4*)&Kg[(size_t)(k0 + 64 + row0) * D_MODEL];
            kr1 = *(const uint4*)&Kg[(size_t)(k0 + 64 + row0 + 32) * D_MODEL];
            vr0 = *(const uint4*)&Vg[(size_t)row0 * SEQ + k0 + 64];
            vr1 = *(const uint4*)&Vg[(size_t)(row0 + 32) * SEQ + k0 + 64];
        }
        float mbv[4];
#pragma unroll
        for (int ct = 0; ct < 4; ++ct) mbv[ct] = mbp[k0 + ct * 16 + l15];

        f32x4 sacc[4];
#pragma unroll
        for (int ct = 0; ct < 4; ++ct) sacc[ct] = (f32x4){0.f, 0.f, 0.f, 0.f};
#pragma unroll
        for (int ct = 0; ct < 4; ++ct) {
            s16x8 b0 = *(const s16x8*)&Ks[(ct * 16 + l15) * 72 + l4 * 8];
            s16x8 b1 = *(const s16x8*)&Ks[(ct * 16 + l15) * 72 + 32 + l4 * 8];
            sacc[ct] = __builtin_amdgcn_mfma_f32_16x16x32_bf16(qf0, b0, sacc[ct], 0, 0, 0);
            sacc[ct] = __builtin_amdgcn_mfma_f32_16x16x32_bf16(qf1, b1, sacc[ct], 0, 0, 0);
        }

#pragma unroll
        for (int ct = 0; ct < 4; ++ct) {
            float p0 = __builtin_amdgcn_exp2f(fmaf(sacc[ct][0], CSC, mbv[ct]));
            float p1 = __builtin_amdgcn_exp2f(fmaf(sacc[ct][1], CSC, mbv[ct]));
            float p2 = __builtin_amdgcn_exp2f(fmaf(sacc[ct][2], CSC, mbv[ct]));
            float p3 = __builtin_amdgcn_exp2f(fmaf(sacc[ct][3], CSC, mbv[ct]));
            lpart[0] += p0; lpart[1] += p1; lpart[2] += p2; lpart[3] += p3;
            unsigned u01 = cvt_pk_bf16(p0, p1);
            unsigned u23 = cvt_pk_bf16(p2, p3);
            int base = (w * 16 + l4 * 4) * 72 + ct * 16 + l15;
            Ps[base]       = (ushort_t)u01;
            Ps[base + 72]  = (ushort_t)(u01 >> 16);
            Ps[base + 144] = (ushort_t)u23;
            Ps[base + 216] = (ushort_t)(u23 >> 16);
        }

#pragma unroll
        for (int ks = 0; ks < 2; ++ks) {
            s16x8 af = *(const s16x8*)&Ps[(w * 16 + l15) * 72 + ks * 32 + l4 * 8];
#pragma unroll
            for (int dt = 0; dt < 4; ++dt) {
                s16x8 bf = *(const s16x8*)&Vs[(dt * 16 + l15) * 72 + ks * 32 + l4 * 8];
                oacc[dt] = __builtin_amdgcn_mfma_f32_16x16x32_bf16(af, bf, oacc[dt], 0, 0, 0);
            }
        }
    }

#pragma unroll
    for (int r = 0; r < 4; ++r) {
        lpart[r] += __shfl_xor(lpart[r], 1);
        lpart[r] += __shfl_xor(lpart[r], 2);
        lpart[r] += __shfl_xor(lpart[r], 4);
        lpart[r] += __shfl_xor(lpart[r], 8);
    }
    const size_t obase = ((size_t)b * SEQ + q0 + w * 16 + l4 * 4) * D_MODEL + h * DKH + l15;
#pragma unroll
    for (int r = 0; r < 4; ++r) {
        float inv = 1.f / lpart[r];
#pragma unroll
        for (int dt = 0; dt < 4; ++dt)
            Ctx[obase + (size_t)r * D_MODEL + dt * 16] = f2bf(oacc[dt][r] * inv);
    }
}

extern "C" void kernel_launch(void* const* d_in, const int* in_sizes, int n_in,
                              void* d_out, int out_size, void* d_ws, size_t ws_size,
                              hipStream_t stream) {
    const float* q    = (const float*)d_in[0];
    const float* k    = (const float*)d_in[1];
    const float* v    = (const float*)d_in[2];
    const int*   mask = (const int*)  d_in[3];
    const float* Wq   = (const float*)d_in[4];
    const float* bq   = (const float*)d_in[5];
    const float* Wk   = (const float*)d_in[6];
    const float* bk   = (const float*)d_in[7];
    const float* Wv   = (const float*)d_in[8];
    const float* bv   = (const float*)d_in[9];
    const float* Wo   = (const float*)d_in[10];
    const float* bo   = (const float*)d_in[11];
    float* out = (float*)d_out;

    char* ws = (char*)d_ws;
    ushort_t* Wqb  = (ushort_t*)(ws);                 //  0- 2 MB
    ushort_t* Wkb  = (ushort_t*)(ws + ( 2u << 20));   //  2- 4
    ushort_t* Wvb  = (ushort_t*)(ws + ( 4u << 20));   //  4- 6
    ushort_t* Wohi = (ushort_t*)(ws + ( 6u << 20));   //  6- 8
    ushort_t* Wolo = (ushort_t*)(ws + ( 8u << 20));   //  8-10
    float*    mb   = (float*)   (ws + (10u << 20));   // 10-12 (16KB used)
    ushort_t* qb   = (ushort_t*)(ws + (12u << 20));   // 12-20
    ushort_t* kb   = (ushort_t*)(ws + (20u << 20));   // 20-28
    ushort_t* vb   = (ushort_t*)(ws + (28u << 20));   // 28-36
    ushort_t* Qb   = (ushort_t*)(ws + (36u << 20));   // 36-44
    ushort_t* Kb   = (ushort_t*)(ws + (44u << 20));   // 44-52
    ushort_t* Vtb  = (ushort_t*)(ws + (52u << 20));   // 52-60
    ushort_t* Ctx  = qb;   // alias: qb free after gemm_qkv consumes it

    convert_all<<<2048, 256, 0, stream>>>(q, k, v, Wq, Wk, Wv, Wo, mask,
                                          qb, kb, vb, Wqb, Wkb, Wvb,
                                          Wohi, Wolo, mb);

    dim3 qkvgrid(D_MODEL / 128, TOK / 128, 3);
    gemm_qkv<<<qkvgrid, 256, 0, stream>>>(qb, kb, vb, Wqb, Wkb, Wvb,
                                          bq, bk, bv, Qb, Kb, Vtb);

    dim3 agrid(BATCH * NHEAD, SEQ / 64);   // x=bh -> XCD-local K/V reuse
    flash2<<<agrid, 256, 0, stream>>>(Qb, Kb, Vtb, mb, Ctx);

    dim3 ogrid(D_MODEL / 64, TOK / 128);
    gemm_out<<<ogrid, 256, 0, stream>>>(Ctx, Wohi, Wolo, bo, out);
}

// Round 14
// 156.509 us; speedup vs baseline: 1.8466x; 1.0107x over previous
//
#include <hip/hip_runtime.h>
#include <math.h>

#define D_MODEL 1024
#define NHEAD   16
#define DKH     64
#define SEQ     2048
#define BATCH   2
#define TOK     (BATCH*SEQ)   // 4096

typedef short s16x8 __attribute__((ext_vector_type(8)));
typedef float f32x4 __attribute__((ext_vector_type(4)));
typedef unsigned short ushort_t;

__device__ inline unsigned short f2bf(float f) {
    union { float f; unsigned u; } v; v.f = f;
    unsigned r = v.u + 0x7FFFu + ((v.u >> 16) & 1u);   // RNE
    return (unsigned short)(r >> 16);
}
__device__ inline float bf2f(ushort_t h) {
    union { unsigned u; float f; } v; v.u = (unsigned)h << 16;
    return v.f;
}
__device__ inline unsigned cvt_pk_bf16(float a, float b) {  // low16=bf16(a), high16=bf16(b)
    unsigned r;
    asm("v_cvt_pk_bf16_f32 %0, %1, %2" : "=v"(r) : "v"(a), "v"(b));
    return r;
}
__device__ inline void gload16(const void* g, void* l) {
    __builtin_amdgcn_global_load_lds(
        (const __attribute__((address_space(1))) void*)g,
        (__attribute__((address_space(3))) void*)l, 16, 0, 0);
}

// ---------------------------------------------------------------------------
// fp32->bf16: q,k,v and Wq,Wk,Wv plain; Wo as hi+lo split; mask -> float bias.
// ---------------------------------------------------------------------------
__global__ __launch_bounds__(256) void convert_all(
    const float* __restrict__ q, const float* __restrict__ k,
    const float* __restrict__ v,
    const float* __restrict__ Wq, const float* __restrict__ Wk,
    const float* __restrict__ Wv, const float* __restrict__ Wo,
    const int* __restrict__ mask,
    ushort_t* __restrict__ qb, ushort_t* __restrict__ kb,
    ushort_t* __restrict__ vb,
    ushort_t* __restrict__ Wqb, ushort_t* __restrict__ Wkb,
    ushort_t* __restrict__ Wvb, ushort_t* __restrict__ Wohi,
    ushort_t* __restrict__ Wolo, float* __restrict__ mb)
{
    const int ACT4 = TOK * D_MODEL / 4;       // 1048576
    const int W4   = D_MODEL * D_MODEL / 4;   // 262144
    const int total = 3 * ACT4 + 4 * W4 + TOK / 4;
    for (int u = blockIdx.x * 256 + threadIdx.x; u < total; u += gridDim.x * 256) {
        if (u < 3 * ACT4) {
            int which = u / ACT4, off = u - which * ACT4;
            const float* src = which == 0 ? q : which == 1 ? k : v;
            ushort_t*    dst = which == 0 ? qb : which == 1 ? kb : vb;
            float4 f = ((const float4*)src)[off];
            uint2 o;
            o.x = cvt_pk_bf16(f.x, f.y);
            o.y = cvt_pk_bf16(f.z, f.w);
            ((uint2*)dst)[off] = o;
        } else if (u < 3 * ACT4 + 3 * W4) {
            int uu = u - 3 * ACT4;
            int which = uu / W4, off = uu - which * W4;
            const float* src = which == 0 ? Wq : which == 1 ? Wk : Wv;
            ushort_t*    dst = which == 0 ? Wqb : which == 1 ? Wkb : Wvb;
            float4 f = ((const float4*)src)[off];
            uint2 o;
            o.x = cvt_pk_bf16(f.x, f.y);
            o.y = cvt_pk_bf16(f.z, f.w);
            ((uint2*)dst)[off] = o;
        } else if (u < 3 * ACT4 + 4 * W4) {
            int off = u - (3 * ACT4 + 3 * W4);
            float4 f = ((const float4*)Wo)[off];
            ushort_t h0 = f2bf(f.x), h1 = f2bf(f.y), h2 = f2bf(f.z), h3 = f2bf(f.w);
            uint2 hw;
            hw.x = (unsigned)h0 | ((unsigned)h1 << 16);
            hw.y = (unsigned)h2 | ((unsigned)h3 << 16);
            ((uint2*)Wohi)[off] = hw;
            uint2 lw;
            lw.x = cvt_pk_bf16(f.x - bf2f(h0), f.y - bf2f(h1));
            lw.y = cvt_pk_bf16(f.z - bf2f(h2), f.w - bf2f(h3));
            ((uint2*)Wolo)[off] = lw;
        } else {
            int off = u - (3 * ACT4 + 4 * W4);
            int4 m = ((const int4*)mask)[off];
            float4 f;
            f.x = m.x ? 0.f : -1e9f;
            f.y = m.y ? 0.f : -1e9f;
            f.z = m.z ? 0.f : -1e9f;
            f.w = m.w ? 0.f : -1e9f;
            ((float4*)mb)[off] = f;
        }
    }
}

// ---------------------------------------------------------------------------
// Fused Q/K/V projection GEMM, pure bf16 (m97 structure): blockIdx.z = {q,k,v}.
// BM=128 BN=128 BK=32, 256 thr, wave-tile 64x64, global_load_lds staging,
// chunked XCD swizzle. z<2 -> row-major bf16; z==2 -> [b][h][d][s].
// ---------------------------------------------------------------------------
__global__ __launch_bounds__(256) void gemm_qkv(
    const ushort_t* __restrict__ qb, const ushort_t* __restrict__ kb,
    const ushort_t* __restrict__ vb,
    const ushort_t* __restrict__ Wqb, const ushort_t* __restrict__ Wkb,
    const ushort_t* __restrict__ Wvb,
    const float* __restrict__ bqp, const float* __restrict__ bkp,
    const float* __restrict__ bvp,
    ushort_t* __restrict__ Qb, ushort_t* __restrict__ Kb,
    ushort_t* __restrict__ Vtb)
{
    __shared__ __align__(16) char pool[64 * 136 * 2];   // 16KB staging / 17KB epi
    ushort_t* As = (ushort_t*)pool;                     // [128][32]
    ushort_t* Ws = As + 128 * 32;                       // [128][32]

    const int z = blockIdx.z;
    const ushort_t* Ain  = z == 0 ? qb : z == 1 ? kb : vb;
    const ushort_t* Wptr = z == 0 ? Wqb : z == 1 ? Wkb : Wvb;
    const float*    bias = z == 0 ? bqp : z == 1 ? bkp : bvp;

    const int hwid = blockIdx.x + 8 * blockIdx.y;       // 0..255, XCD = hwid%8
    const int work = (hwid & 7) * 32 + (hwid >> 3);
    const int m0 = (work >> 3) * 128;
    const int n0 = (work & 7) * 128;

    const int t = threadIdx.x;
    const int w = t >> 6, lane = t & 63, l15 = lane & 15, l4 = lane >> 4;
    const int wr = w >> 1, wc = w & 1;

    f32x4 acc[4][4];
#pragma unroll
    for (int m = 0; m < 4; ++m)
#pragma unroll
        for (int n = 0; n < 4; ++n) acc[m][n] = (f32x4){0.f, 0.f, 0.f, 0.f};

    const ushort_t* Ag = Ain  + (size_t)(m0 + (t >> 2)) * D_MODEL + (t & 3) * 8;
    const ushort_t* Wg = Wptr + (size_t)(n0 + (t >> 2)) * D_MODEL + (t & 3) * 8;
    ushort_t* AsW = As + w * 512;
    ushort_t* WsW = Ws + w * 512;

    for (int k0 = 0; k0 < D_MODEL; k0 += 32) {
        __syncthreads();
        gload16(Ag + k0, AsW);
        gload16(Ag + (size_t)64 * D_MODEL + k0, AsW + 2048);
        gload16(Wg + k0, WsW);
        gload16(Wg + (size_t)64 * D_MODEL + k0, WsW + 2048);
        __syncthreads();

        s16x8 af[4], bfr[4];
#pragma unroll
        for (int m = 0; m < 4; ++m)
            af[m] = *(const s16x8*)&As[(wr * 64 + m * 16 + l15) * 32 + l4 * 8];
#pragma unroll
        for (int n = 0; n < 4; ++n)
            bfr[n] = *(const s16x8*)&Ws[(wc * 64 + n * 16 + l15) * 32 + l4 * 8];
#pragma unroll
        for (int m = 0; m < 4; ++m)
#pragma unroll
            for (int n = 0; n < 4; ++n)
                acc[m][n] = __builtin_amdgcn_mfma_f32_16x16x32_bf16(af[m], bfr[n], acc[m][n], 0, 0, 0);
    }

    if (z == 2) {   // transposed per-head epilogue -> Vtb[b][h][d][s], 2 halves
        ushort_t* Ct = (ushort_t*)pool;   // [64][136]
        const int h0 = n0 >> 6;
        const int bb = m0 >> 11;
        const int s0 = m0 & (SEQ - 1);
#pragma unroll
        for (int hh = 0; hh < 2; ++hh) {
            __syncthreads();
            if (wc == hh) {
#pragma unroll
                for (int n = 0; n < 4; ++n) {
                    const int nl = n * 16 + l15;
                    const float bv = bias[n0 + hh * 64 + nl];
#pragma unroll
                    for (int m = 0; m < 4; ++m) {
                        const int ml = wr * 64 + m * 16 + l4 * 4;
#pragma unroll
                        for (int r = 0; r < 4; ++r)
                            Ct[nl * 136 + ml + r] = f2bf(acc[m][n][r] + bv);
                    }
                }
            }
            __syncthreads();
            const int dl = t >> 2;
            ushort_t* dst = Vtb + (((size_t)bb * NHEAD + h0 + hh) * DKH + dl) * SEQ + s0;
#pragma unroll
            for (int c = 0; c < 4; ++c) {
                int chk = (t & 3) + c * 4;
                *(uint4*)&dst[chk * 8] = *(const uint4*)&Ct[dl * 136 + chk * 8];
            }
        }
    } else {
        ushort_t* Cout = z == 0 ? Qb : Kb;
#pragma unroll
        for (int n = 0; n < 4; ++n) {
            const int col = n0 + wc * 64 + n * 16 + l15;
            const float bv = bias[col];
#pragma unroll
            for (int m = 0; m < 4; ++m) {
                const int row = m0 + wr * 64 + m * 16 + l4 * 4;
#pragma unroll
                for (int r = 0; r < 4; ++r)
                    Cout[(size_t)(row + r) * D_MODEL + col] = f2bf(acc[m][n][r] + bv);
            }
        }
    }
}

// ---------------------------------------------------------------------------
// Output projection GEMM: C[TOK][D] fp32 = Ctx_bf16 @ (Wohi + Wolo)^T + bias.
// BM=128 BN=64 BK=32, 256 thr, global_load_lds staging + chunked XCD swizzle.
// ---------------------------------------------------------------------------
__global__ __launch_bounds__(256) void gemm_out(
    const ushort_t* __restrict__ Ain, const ushort_t* __restrict__ Wptr,
    const ushort_t* __restrict__ W2ptr, const float* __restrict__ bias,
    float* __restrict__ Cout)
{
    __shared__ ushort_t As[128 * 32];
    __shared__ ushort_t Ws[64 * 32];
    __shared__ ushort_t Ws2[64 * 32];

    const int hwid = blockIdx.x + 16 * blockIdx.y;
    const int work = (hwid & 7) * 64 + (hwid >> 3);
    const int m0 = (work >> 4) * 128;
    const int n0 = (work & 15) * 64;

    const int t = threadIdx.x;
    const int w = t >> 6, lane = t & 63, l15 = lane & 15, l4 = lane >> 4;
    const int wr = w >> 1, wc = w & 1;

    f32x4 acc[4][2];
#pragma unroll
    for (int m = 0; m < 4; ++m)
#pragma unroll
        for (int n = 0; n < 2; ++n) acc[m][n] = (f32x4){0.f, 0.f, 0.f, 0.f};

    const ushort_t* Ag  = Ain   + (size_t)(m0 + (t >> 2)) * D_MODEL + (t & 3) * 8;
    const ushort_t* Wg  = Wptr  + (size_t)(n0 + (t >> 2)) * D_MODEL + (t & 3) * 8;
    const ushort_t* W2g = W2ptr + (size_t)(n0 + (t >> 2)) * D_MODEL + (t & 3) * 8;
    ushort_t* AsW = As + w * 512;
    ushort_t* WsW = Ws + w * 512;
    ushort_t* Ws2W = Ws2 + w * 512;

    for (int k0 = 0; k0 < D_MODEL; k0 += 32) {
        __syncthreads();
        gload16(Ag + k0, AsW);
        gload16(Ag + (size_t)64 * D_MODEL + k0, AsW + 2048);
        gload16(Wg + k0, WsW);
        gload16(W2g + k0, Ws2W);
        __syncthreads();

        s16x8 af[4], bfr[2], bfr2[2];
#pragma unroll
        for (int m = 0; m < 4; ++m)
            af[m] = *(const s16x8*)&As[(wr * 64 + m * 16 + l15) * 32 + l4 * 8];
#pragma unroll
        for (int n = 0; n < 2; ++n) {
            bfr[n]  = *(const s16x8*)&Ws[(wc * 32 + n * 16 + l15) * 32 + l4 * 8];
            bfr2[n] = *(const s16x8*)&Ws2[(wc * 32 + n * 16 + l15) * 32 + l4 * 8];
        }
#pragma unroll
        for (int m = 0; m < 4; ++m)
#pragma unroll
            for (int n = 0; n < 2; ++n) {
                acc[m][n] = __builtin_amdgcn_mfma_f32_16x16x32_bf16(af[m], bfr[n],  acc[m][n], 0, 0, 0);
                acc[m][n] = __builtin_amdgcn_mfma_f32_16x16x32_bf16(af[m], bfr2[n], acc[m][n], 0, 0, 0);
            }
    }

#pragma unroll
    for (int n = 0; n < 2; ++n) {
        const int col = n0 + wc * 32 + n * 16 + l15;
        const float bv = bias[col];
#pragma unroll
        for (int m = 0; m < 4; ++m) {
            const int row = m0 + wr * 64 + m * 16 + l4 * 4;
#pragma unroll
            for (int r = 0; r < 4; ++r)
                Cout[(size_t)(row + r) * D_MODEL + col] = acc[m][n][r] + bv;
        }
    }
}

// ---------------------------------------------------------------------------
// Flash attention (round-11 flash2, byte-identical inner loop) + T5 setprio:
// MFMA clusters wrapped in s_setprio(1)/(0). 1024 independent blocks at
// different loop phases -> scheduler favors the MFMA-issuing wave (attn-proven
// +4-7%, m191). Pure scheduler hint; zero semantic effect.
// ---------------------------------------------------------------------------
__global__ __launch_bounds__(256) void flash2(
    const ushort_t* __restrict__ Q, const ushort_t* __restrict__ K,
    const ushort_t* __restrict__ Vt, const float* __restrict__ mb,
    ushort_t* __restrict__ Ctx)
{
    __shared__ ushort_t Ks[64 * 72];
    __shared__ ushort_t Vs[64 * 72];
    __shared__ ushort_t Ps[64 * 72];

    const int t = threadIdx.x;
    const int w = t >> 6, lane = t & 63, l15 = lane & 15, l4 = lane >> 4;
    const int q0 = blockIdx.y * 64;
    const int bh = blockIdx.x, b = bh >> 4, h = bh & 15;

    s16x8 qf0, qf1;
    {
        const ushort_t* qp = Q + ((size_t)b * SEQ + q0 + w * 16 + l15) * D_MODEL + h * DKH + l4 * 8;
        qf0 = *(const s16x8*)qp;
        qf1 = *(const s16x8*)(qp + 32);
    }

    f32x4 oacc[4];
#pragma unroll
    for (int dt = 0; dt < 4; ++dt) oacc[dt] = (f32x4){0.f, 0.f, 0.f, 0.f};
    float lpart[4] = {0.f, 0.f, 0.f, 0.f};

    const int ch   = t & 7;
    const int row0 = t >> 3;
    const ushort_t* Kg = K  + ((size_t)b * SEQ) * D_MODEL + h * DKH + ch * 8;
    const ushort_t* Vg = Vt + ((size_t)bh * DKH) * SEQ + ch * 8;

    uint4 kr0 = *(const uint4*)&Kg[(size_t)row0 * D_MODEL];
    uint4 kr1 = *(const uint4*)&Kg[(size_t)(row0 + 32) * D_MODEL];
    uint4 vr0 = *(const uint4*)&Vg[(size_t)row0 * SEQ];
    uint4 vr1 = *(const uint4*)&Vg[(size_t)(row0 + 32) * SEQ];

    const float CSC = 0.18033688011112042f;   // 0.125 * log2(e)
    const float* mbp = mb + b * SEQ;

    for (int k0 = 0; k0 < SEQ; k0 += 64) {
        __syncthreads();
        *(uint4*)&Ks[row0 * 72 + ch * 8]        = kr0;
        *(uint4*)&Ks[(row0 + 32) * 72 + ch * 8] = kr1;
        *(uint4*)&Vs[row0 * 72 + ch * 8]        = vr0;
        *(uint4*)&Vs[(row0 + 32) * 72 + ch * 8] = vr1;
        __syncthreads();
        if (k0 + 64 < SEQ) {
            kr0 = *(const uint4*)&Kg[(size_t)(k0 + 64 + row0) * D_MODEL];
            kr1 = *(const uint4*)&Kg[(size_t)(k0 + 64 + row0 + 32) * D_MODEL];
            vr0 = *(const uint4*)&Vg[(size_t)row0 * SEQ + k0 + 64];
            vr1 = *(const uint4*)&Vg[(size_t)(row0 + 32) * SEQ + k0 + 64];
        }
        float mbv[4];
#pragma unroll
        for (int ct = 0; ct < 4; ++ct) mbv[ct] = mbp[k0 + ct * 16 + l15];

        f32x4 sacc[4];
#pragma unroll
        for (int ct = 0; ct < 4; ++ct) sacc[ct] = (f32x4){0.f, 0.f, 0.f, 0.f};
        __builtin_amdgcn_s_setprio(1);
#pragma unroll
        for (int ct = 0; ct < 4; ++ct) {
            s16x8 b0 = *(const s16x8*)&Ks[(ct * 16 + l15) * 72 + l4 * 8];
            s16x8 b1 = *(const s16x8*)&Ks[(ct * 16 + l15) * 72 + 32 + l4 * 8];
            sacc[ct] = __builtin_amdgcn_mfma_f32_16x16x32_bf16(qf0, b0, sacc[ct], 0, 0, 0);
            sacc[ct] = __builtin_amdgcn_mfma_f32_16x16x32_bf16(qf1, b1, sacc[ct], 0, 0, 0);
        }
        __builtin_amdgcn_s_setprio(0);

#pragma unroll
        for (int ct = 0; ct < 4; ++ct) {
            float p0 = __builtin_amdgcn_exp2f(fmaf(sacc[ct][0], CSC, mbv[ct]));
            float p1 = __builtin_amdgcn_exp2f(fmaf(sacc[ct][1], CSC, mbv[ct]));
            float p2 = __builtin_amdgcn_exp2f(fmaf(sacc[ct][2], CSC, mbv[ct]));
            float p3 = __builtin_amdgcn_exp2f(fmaf(sacc[ct][3], CSC, mbv[ct]));
            lpart[0] += p0; lpart[1] += p1; lpart[2] += p2; lpart[3] += p3;
            unsigned u01 = cvt_pk_bf16(p0, p1);
            unsigned u23 = cvt_pk_bf16(p2, p3);
            int base = (w * 16 + l4 * 4) * 72 + ct * 16 + l15;
            Ps[base]       = (ushort_t)u01;
            Ps[base + 72]  = (ushort_t)(u01 >> 16);
            Ps[base + 144] = (ushort_t)u23;
            Ps[base + 216] = (ushort_t)(u23 >> 16);
        }

        __builtin_amdgcn_s_setprio(1);
#pragma unroll
        for (int ks = 0; ks < 2; ++ks) {
            s16x8 af = *(const s16x8*)&Ps[(w * 16 + l15) * 72 + ks * 32 + l4 * 8];
#pragma unroll
            for (int dt = 0; dt < 4; ++dt) {
                s16x8 bf = *(const s16x8*)&Vs[(dt * 16 + l15) * 72 + ks * 32 + l4 * 8];
                oacc[dt] = __builtin_amdgcn_mfma_f32_16x16x32_bf16(af, bf, oacc[dt], 0, 0, 0);
            }
        }
        __builtin_amdgcn_s_setprio(0);
    }

#pragma unroll
    for (int r = 0; r < 4; ++r) {
        lpart[r] += __shfl_xor(lpart[r], 1);
        lpart[r] += __shfl_xor(lpart[r], 2);
        lpart[r] += __shfl_xor(lpart[r], 4);
        lpart[r] += __shfl_xor(lpart[r], 8);
    }
    const size_t obase = ((size_t)b * SEQ + q0 + w * 16 + l4 * 4) * D_MODEL + h * DKH + l15;
#pragma unroll
    for (int r = 0; r < 4; ++r) {
        float inv = 1.f / lpart[r];
#pragma unroll
        for (int dt = 0; dt < 4; ++dt)
            Ctx[obase + (size_t)r * D_MODEL + dt * 16] = f2bf(oacc[dt][r] * inv);
    }
}

extern "C" void kernel_launch(void* const* d_in, const int* in_sizes, int n_in,
                              void* d_out, int out_size, void* d_ws, size_t ws_size,
                              hipStream_t stream) {
    const float* q    = (const float*)d_in[0];
    const float* k    = (const float*)d_in[1];
    const float* v    = (const float*)d_in[2];
    const int*   mask = (const int*)  d_in[3];
    const float* Wq   = (const float*)d_in[4];
    const float* bq   = (const float*)d_in[5];
    const float* Wk   = (const float*)d_in[6];
    const float* bk   = (const float*)d_in[7];
    const float* Wv   = (const float*)d_in[8];
    const float* bv   = (const float*)d_in[9];
    const float* Wo   = (const float*)d_in[10];
    const float* bo   = (const float*)d_in[11];
    float* out = (float*)d_out;

    char* ws = (char*)d_ws;
    ushort_t* Wqb  = (ushort_t*)(ws);                 //  0- 2 MB
    ushort_t* Wkb  = (ushort_t*)(ws + ( 2u << 20));   //  2- 4
    ushort_t* Wvb  = (ushort_t*)(ws + ( 4u << 20));   //  4- 6
    ushort_t* Wohi = (ushort_t*)(ws + ( 6u << 20));   //  6- 8
    ushort_t* Wolo = (ushort_t*)(ws + ( 8u << 20));   //  8-10
    float*    mb   = (float*)   (ws + (10u << 20));   // 10-12 (16KB used)
    ushort_t* qb   = (ushort_t*)(ws + (12u << 20));   // 12-20
    ushort_t* kb   = (ushort_t*)(ws + (20u << 20));   // 20-28
    ushort_t* vb   = (ushort_t*)(ws + (28u << 20));   // 28-36
    ushort_t* Qb   = (ushort_t*)(ws + (36u << 20));   // 36-44
    ushort_t* Kb   = (ushort_t*)(ws + (44u << 20));   // 44-52
    ushort_t* Vtb  = (ushort_t*)(ws + (52u << 20));   // 52-60
    ushort_t* Ctx  = qb;   // alias: qb free after gemm_qkv consumes it

    convert_all<<<2048, 256, 0, stream>>>(q, k, v, Wq, Wk, Wv, Wo, mask,
                                          qb, kb, vb, Wqb, Wkb, Wvb,
                                          Wohi, Wolo, mb);

    dim3 qkvgrid(D_MODEL / 128, TOK / 128, 3);
    gemm_qkv<<<qkvgrid, 256, 0, stream>>>(qb, kb, vb, Wqb, Wkb, Wvb,
                                          bq, bk, bv, Qb, Kb, Vtb);

    dim3 agrid(BATCH * NHEAD, SEQ / 64);   // x=bh -> XCD-local K/V reuse
    flash2<<<agrid, 256, 0, stream>>>(Qb, Kb, Vtb, mb, Ctx);

    dim3 ogrid(D_MODEL / 64, TOK / 128);
    gemm_out<<<ogrid, 256, 0, stream>>>(Ctx, Wohi, Wolo, bo, out);
}

// Round 15
// 150.555 us; speedup vs baseline: 1.9196x; 1.0396x over previous
//
#include <hip/hip_runtime.h>
#include <math.h>

#define D_MODEL 1024
#define NHEAD   16
#define DKH     64
#define SEQ     2048
#define BATCH   2
#define TOK     (BATCH*SEQ)   // 4096

typedef short s16x8 __attribute__((ext_vector_type(8)));
typedef float f32x4 __attribute__((ext_vector_type(4)));
typedef float f32x16 __attribute__((ext_vector_type(16)));
typedef unsigned short ushort_t;

__device__ inline unsigned short f2bf(float f) {
    union { float f; unsigned u; } v; v.f = f;
    unsigned r = v.u + 0x7FFFu + ((v.u >> 16) & 1u);   // RNE
    return (unsigned short)(r >> 16);
}
__device__ inline float bf2f(ushort_t h) {
    union { unsigned u; float f; } v; v.u = (unsigned)h << 16;
    return v.f;
}
__device__ inline unsigned cvt_pk_bf16(float a, float b) {  // low16=bf16(a), high16=bf16(b)
    unsigned r;
    asm("v_cvt_pk_bf16_f32 %0, %1, %2" : "=v"(r) : "v"(a), "v"(b));
    return r;
}
__device__ inline void gload16(const void* g, void* l) {
    __builtin_amdgcn_global_load_lds(
        (const __attribute__((address_space(1))) void*)g,
        (__attribute__((address_space(3))) void*)l, 16, 0, 0);
}
__device__ inline f32x16 zero16() {
    f32x16 v;
#pragma unroll
    for (int i = 0; i < 16; ++i) v[i] = 0.f;
    return v;
}

// ---------------------------------------------------------------------------
// fp32->bf16: q,k,v and Wq,Wk,Wv plain; Wo as hi+lo split; mask -> float bias.
// ---------------------------------------------------------------------------
__global__ __launch_bounds__(256) void convert_all(
    const float* __restrict__ q, const float* __restrict__ k,
    const float* __restrict__ v,
    const float* __restrict__ Wq, const float* __restrict__ Wk,
    const float* __restrict__ Wv, const float* __restrict__ Wo,
    const int* __restrict__ mask,
    ushort_t* __restrict__ qb, ushort_t* __restrict__ kb,
    ushort_t* __restrict__ vb,
    ushort_t* __restrict__ Wqb, ushort_t* __restrict__ Wkb,
    ushort_t* __restrict__ Wvb, ushort_t* __restrict__ Wohi,
    ushort_t* __restrict__ Wolo, float* __restrict__ mb)
{
    const int ACT4 = TOK * D_MODEL / 4;       // 1048576
    const int W4   = D_MODEL * D_MODEL / 4;   // 262144
    const int total = 3 * ACT4 + 4 * W4 + TOK / 4;
    for (int u = blockIdx.x * 256 + threadIdx.x; u < total; u += gridDim.x * 256) {
        if (u < 3 * ACT4) {
            int which = u / ACT4, off = u - which * ACT4;
            const float* src = which == 0 ? q : which == 1 ? k : v;
            ushort_t*    dst = which == 0 ? qb : which == 1 ? kb : vb;
            float4 f = ((const float4*)src)[off];
            uint2 o;
            o.x = cvt_pk_bf16(f.x, f.y);
            o.y = cvt_pk_bf16(f.z, f.w);
            ((uint2*)dst)[off] = o;
        } else if (u < 3 * ACT4 + 3 * W4) {
            int uu = u - 3 * ACT4;
            int which = uu / W4, off = uu - which * W4;
            const float* src = which == 0 ? Wq : which == 1 ? Wk : Wv;
            ushort_t*    dst = which == 0 ? Wqb : which == 1 ? Wkb : Wvb;
            float4 f = ((const float4*)src)[off];
            uint2 o;
            o.x = cvt_pk_bf16(f.x, f.y);
            o.y = cvt_pk_bf16(f.z, f.w);
            ((uint2*)dst)[off] = o;
        } else if (u < 3 * ACT4 + 4 * W4) {
            int off = u - (3 * ACT4 + 3 * W4);
            float4 f = ((const float4*)Wo)[off];
            ushort_t h0 = f2bf(f.x), h1 = f2bf(f.y), h2 = f2bf(f.z), h3 = f2bf(f.w);
            uint2 hw;
            hw.x = (unsigned)h0 | ((unsigned)h1 << 16);
            hw.y = (unsigned)h2 | ((unsigned)h3 << 16);
            ((uint2*)Wohi)[off] = hw;
            uint2 lw;
            lw.x = cvt_pk_bf16(f.x - bf2f(h0), f.y - bf2f(h1));
            lw.y = cvt_pk_bf16(f.z - bf2f(h2), f.w - bf2f(h3));
            ((uint2*)Wolo)[off] = lw;
        } else {
            int off = u - (3 * ACT4 + 4 * W4);
            int4 m = ((const int4*)mask)[off];
            float4 f;
            f.x = m.x ? 0.f : -1e9f;
            f.y = m.y ? 0.f : -1e9f;
            f.z = m.z ? 0.f : -1e9f;
            f.w = m.w ? 0.f : -1e9f;
            ((float4*)mb)[off] = f;
        }
    }
}

// ---------------------------------------------------------------------------
// Fused Q/K/V projection GEMM, pure bf16 (m97 structure): blockIdx.z = {q,k,v}.
// BM=128 BN=128 BK=32, 256 thr, wave-tile 64x64, global_load_lds staging,
// chunked XCD swizzle. z<2 -> row-major bf16; z==2 -> [b][h][d][s].
// ---------------------------------------------------------------------------
__global__ __launch_bounds__(256) void gemm_qkv(
    const ushort_t* __restrict__ qb, const ushort_t* __restrict__ kb,
    const ushort_t* __restrict__ vb,
    const ushort_t* __restrict__ Wqb, const ushort_t* __restrict__ Wkb,
    const ushort_t* __restrict__ Wvb,
    const float* __restrict__ bqp, const float* __restrict__ bkp,
    const float* __restrict__ bvp,
    ushort_t* __restrict__ Qb, ushort_t* __restrict__ Kb,
    ushort_t* __restrict__ Vtb)
{
    __shared__ __align__(16) char pool[64 * 136 * 2];   // 16KB staging / 17KB epi
    ushort_t* As = (ushort_t*)pool;                     // [128][32]
    ushort_t* Ws = As + 128 * 32;                       // [128][32]

    const int z = blockIdx.z;
    const ushort_t* Ain  = z == 0 ? qb : z == 1 ? kb : vb;
    const ushort_t* Wptr = z == 0 ? Wqb : z == 1 ? Wkb : Wvb;
    const float*    bias = z == 0 ? bqp : z == 1 ? bkp : bvp;

    const int hwid = blockIdx.x + 8 * blockIdx.y;       // 0..255, XCD = hwid%8
    const int work = (hwid & 7) * 32 + (hwid >> 3);
    const int m0 = (work >> 3) * 128;
    const int n0 = (work & 7) * 128;

    const int t = threadIdx.x;
    const int w = t >> 6, lane = t & 63, l15 = lane & 15, l4 = lane >> 4;
    const int wr = w >> 1, wc = w & 1;

    f32x4 acc[4][4];
#pragma unroll
    for (int m = 0; m < 4; ++m)
#pragma unroll
        for (int n = 0; n < 4; ++n) acc[m][n] = (f32x4){0.f, 0.f, 0.f, 0.f};

    const ushort_t* Ag = Ain  + (size_t)(m0 + (t >> 2)) * D_MODEL + (t & 3) * 8;
    const ushort_t* Wg = Wptr + (size_t)(n0 + (t >> 2)) * D_MODEL + (t & 3) * 8;
    ushort_t* AsW = As + w * 512;
    ushort_t* WsW = Ws + w * 512;

    for (int k0 = 0; k0 < D_MODEL; k0 += 32) {
        __syncthreads();
        gload16(Ag + k0, AsW);
        gload16(Ag + (size_t)64 * D_MODEL + k0, AsW + 2048);
        gload16(Wg + k0, WsW);
        gload16(Wg + (size_t)64 * D_MODEL + k0, WsW + 2048);
        __syncthreads();

        s16x8 af[4], bfr[4];
#pragma unroll
        for (int m = 0; m < 4; ++m)
            af[m] = *(const s16x8*)&As[(wr * 64 + m * 16 + l15) * 32 + l4 * 8];
#pragma unroll
        for (int n = 0; n < 4; ++n)
            bfr[n] = *(const s16x8*)&Ws[(wc * 64 + n * 16 + l15) * 32 + l4 * 8];
#pragma unroll
        for (int m = 0; m < 4; ++m)
#pragma unroll
            for (int n = 0; n < 4; ++n)
                acc[m][n] = __builtin_amdgcn_mfma_f32_16x16x32_bf16(af[m], bfr[n], acc[m][n], 0, 0, 0);
    }

    if (z == 2) {   // transposed per-head epilogue -> Vtb[b][h][d][s], 2 halves
        ushort_t* Ct = (ushort_t*)pool;   // [64][136]
        const int h0 = n0 >> 6;
        const int bb = m0 >> 11;
        const int s0 = m0 & (SEQ - 1);
#pragma unroll
        for (int hh = 0; hh < 2; ++hh) {
            __syncthreads();
            if (wc == hh) {
#pragma unroll
                for (int n = 0; n < 4; ++n) {
                    const int nl = n * 16 + l15;
                    const float bv = bias[n0 + hh * 64 + nl];
#pragma unroll
                    for (int m = 0; m < 4; ++m) {
                        const int ml = wr * 64 + m * 16 + l4 * 4;
#pragma unroll
                        for (int r = 0; r < 4; ++r)
                            Ct[nl * 136 + ml + r] = f2bf(acc[m][n][r] + bv);
                    }
                }
            }
            __syncthreads();
            const int dl = t >> 2;
            ushort_t* dst = Vtb + (((size_t)bb * NHEAD + h0 + hh) * DKH + dl) * SEQ + s0;
#pragma unroll
            for (int c = 0; c < 4; ++c) {
                int chk = (t & 3) + c * 4;
                *(uint4*)&dst[chk * 8] = *(const uint4*)&Ct[dl * 136 + chk * 8];
            }
        }
    } else {
        ushort_t* Cout = z == 0 ? Qb : Kb;
#pragma unroll
        for (int n = 0; n < 4; ++n) {
            const int col = n0 + wc * 64 + n * 16 + l15;
            const float bv = bias[col];
#pragma unroll
            for (int m = 0; m < 4; ++m) {
                const int row = m0 + wr * 64 + m * 16 + l4 * 4;
#pragma unroll
                for (int r = 0; r < 4; ++r)
                    Cout[(size_t)(row + r) * D_MODEL + col] = f2bf(acc[m][n][r] + bv);
            }
        }
    }
}

// ---------------------------------------------------------------------------
// Output projection GEMM: C[TOK][D] fp32 = Ctx_bf16 @ (Wohi + Wolo)^T + bias.
// BM=128 BN=64 BK=32, 256 thr, global_load_lds staging + chunked XCD swizzle.
// ---------------------------------------------------------------------------
__global__ __launch_bounds__(256) void gemm_out(
    const ushort_t* __restrict__ Ain, const ushort_t* __restrict__ Wptr,
    const ushort_t* __restrict__ W2ptr, const float* __restrict__ bias,
    float* __restrict__ Cout)
{
    __shared__ ushort_t As[128 * 32];
    __shared__ ushort_t Ws[64 * 32];
    __shared__ ushort_t Ws2[64 * 32];

    const int hwid = blockIdx.x + 16 * blockIdx.y;
    const int work = (hwid & 7) * 64 + (hwid >> 3);
    const int m0 = (work >> 4) * 128;
    const int n0 = (work & 15) * 64;

    const int t = threadIdx.x;
    const int w = t >> 6, lane = t & 63, l15 = lane & 15, l4 = lane >> 4;
    const int wr = w >> 1, wc = w & 1;

    f32x4 acc[4][2];
#pragma unroll
    for (int m = 0; m < 4; ++m)
#pragma unroll
        for (int n = 0; n < 2; ++n) acc[m][n] = (f32x4){0.f, 0.f, 0.f, 0.f};

    const ushort_t* Ag  = Ain   + (size_t)(m0 + (t >> 2)) * D_MODEL + (t & 3) * 8;
    const ushort_t* Wg  = Wptr  + (size_t)(n0 + (t >> 2)) * D_MODEL + (t & 3) * 8;
    const ushort_t* W2g = W2ptr + (size_t)(n0 + (t >> 2)) * D_MODEL + (t & 3) * 8;
    ushort_t* AsW = As + w * 512;
    ushort_t* WsW = Ws + w * 512;
    ushort_t* Ws2W = Ws2 + w * 512;

    for (int k0 = 0; k0 < D_MODEL; k0 += 32) {
        __syncthreads();
        gload16(Ag + k0, AsW);
        gload16(Ag + (size_t)64 * D_MODEL + k0, AsW + 2048);
        gload16(Wg + k0, WsW);
        gload16(W2g + k0, Ws2W);
        __syncthreads();

        s16x8 af[4], bfr[2], bfr2[2];
#pragma unroll
        for (int m = 0; m < 4; ++m)
            af[m] = *(const s16x8*)&As[(wr * 64 + m * 16 + l15) * 32 + l4 * 8];
#pragma unroll
        for (int n = 0; n < 2; ++n) {
            bfr[n]  = *(const s16x8*)&Ws[(wc * 32 + n * 16 + l15) * 32 + l4 * 8];
            bfr2[n] = *(const s16x8*)&Ws2[(wc * 32 + n * 16 + l15) * 32 + l4 * 8];
        }
#pragma unroll
        for (int m = 0; m < 4; ++m)
#pragma unroll
            for (int n = 0; n < 2; ++n) {
                acc[m][n] = __builtin_amdgcn_mfma_f32_16x16x32_bf16(af[m], bfr[n],  acc[m][n], 0, 0, 0);
                acc[m][n] = __builtin_amdgcn_mfma_f32_16x16x32_bf16(af[m], bfr2[n], acc[m][n], 0, 0, 0);
            }
    }

#pragma unroll
    for (int n = 0; n < 2; ++n) {
        const int col = n0 + wc * 32 + n * 16 + l15;
        const float bv = bias[col];
#pragma unroll
        for (int m = 0; m < 4; ++m) {
            const int row = m0 + wr * 64 + m * 16 + l4 * 4;
#pragma unroll
            for (int r = 0; r < 4; ++r)
                Cout[(size_t)(row + r) * D_MODEL + col] = acc[m][n][r] + bv;
        }
    }
}

// ---------------------------------------------------------------------------
// Flash attention v5: 32x32x16 MFMA. 4 waves x 32 q-rows = Q-tile 128.
// One wave natively owns 32 q-rows -> B-fragment (K/V) LDS reads amortize
// over 2x the FLOPs of the 16x16 version (-42% LDS bytes per unit work).
// Layouts (m74/m101-verified C/D; A/B by the verified family pattern):
//   A/B frag: row/col = lane&31, k = (lane>>5)*8 + j  (8 contiguous bf16)
//   C/D:      col = lane&31, row = (reg&3) + 8*(reg>>2) + 4*(lane>>5)
// P path: scalar ushort stores + sched_barrier(0) (flash3f-proven combo).
// No online max (scores bounded); row sums deferred to epilogue.
// Grid (x=bh, y=qtile/128) keeps XCD-local K/V reuse.
// ---------------------------------------------------------------------------
__global__ __launch_bounds__(256) void flash5(
    const ushort_t* __restrict__ Q, const ushort_t* __restrict__ K,
    const ushort_t* __restrict__ Vt, const float* __restrict__ mb,
    ushort_t* __restrict__ Ctx)
{
    __shared__ ushort_t Ks[64 * 72];
    __shared__ ushort_t Vs[64 * 72];
    __shared__ ushort_t Ps[128 * 72];

    const int t = threadIdx.x;
    const int w = t >> 6, lane = t & 63;
    const int l31 = lane & 31, lh = lane >> 5;
    const int q0 = blockIdx.y * 128;
    const int bh = blockIdx.x, b = bh >> 4, h = bh & 15;

    // Q fragments: A-operand rows = q0 + w*32 + l31, k-chunk = ks*16 + lh*8
    s16x8 qf[4];
    {
        const ushort_t* qp = Q + ((size_t)b * SEQ + q0 + w * 32 + l31) * D_MODEL + h * DKH + lh * 8;
#pragma unroll
        for (int ks = 0; ks < 4; ++ks)
            qf[ks] = *(const s16x8*)(qp + ks * 16);
    }

    f32x16 oacc0 = zero16(), oacc1 = zero16();
    float lpart[16];
#pragma unroll
    for (int i = 0; i < 16; ++i) lpart[i] = 0.f;

    const int ch   = t & 7;
    const int row0 = t >> 3;
    const ushort_t* Kg = K  + ((size_t)b * SEQ) * D_MODEL + h * DKH + ch * 8;
    const ushort_t* Vg = Vt + ((size_t)bh * DKH) * SEQ + ch * 8;

    uint4 kr0 = *(const uint4*)&Kg[(size_t)row0 * D_MODEL];
    uint4 kr1 = *(const uint4*)&Kg[(size_t)(row0 + 32) * D_MODEL];
    uint4 vr0 = *(const uint4*)&Vg[(size_t)row0 * SEQ];
    uint4 vr1 = *(const uint4*)&Vg[(size_t)(row0 + 32) * SEQ];

    const float CSC = 0.18033688011112042f;   // 0.125 * log2(e)
    const float* mbp = mb + b * SEQ;
    const int prow = w * 32;                  // wave's private Ps row base

    for (int k0 = 0; k0 < SEQ; k0 += 64) {
        __syncthreads();
        *(uint4*)&Ks[row0 * 72 + ch * 8]        = kr0;
        *(uint4*)&Ks[(row0 + 32) * 72 + ch * 8] = kr1;
        *(uint4*)&Vs[row0 * 72 + ch * 8]        = vr0;
        *(uint4*)&Vs[(row0 + 32) * 72 + ch * 8] = vr1;
        __syncthreads();
        if (k0 + 64 < SEQ) {
            kr0 = *(const uint4*)&Kg[(size_t)(k0 + 64 + row0) * D_MODEL];
            kr1 = *(const uint4*)&Kg[(size_t)(k0 + 64 + row0 + 32) * D_MODEL];
            vr0 = *(const uint4*)&Vg[(size_t)row0 * SEQ + k0 + 64];
            vr1 = *(const uint4*)&Vg[(size_t)(row0 + 32) * SEQ + k0 + 64];
        }
        const float mb0 = mbp[k0 + l31];
        const float mb1 = mbp[k0 + 32 + l31];

        // ---- S = Q K^T : two 32x32 key-blocks, K dim = 64 (4 x 16) ----
        f32x16 sacc0 = zero16(), sacc1 = zero16();
        __builtin_amdgcn_s_setprio(1);
#pragma unroll
        for (int ks = 0; ks < 4; ++ks) {
            s16x8 kf0 = *(const s16x8*)&Ks[(l31)      * 72 + ks * 16 + lh * 8];
            s16x8 kf1 = *(const s16x8*)&Ks[(32 + l31) * 72 + ks * 16 + lh * 8];
            sacc0 = __builtin_amdgcn_mfma_f32_32x32x16_bf16(qf[ks], kf0, sacc0, 0, 0, 0);
            sacc1 = __builtin_amdgcn_mfma_f32_32x32x16_bf16(qf[ks], kf1, sacc1, 0, 0, 0);
        }
        __builtin_amdgcn_s_setprio(0);

        // ---- P = exp2(S*CSC + maskbias), bf16 scalar stores to Ps[q][key] ----
        // reg pair (2rp, 2rp+1) -> consecutive rows (rows = (r&3)+8*(r>>2)+4*lh)
#pragma unroll
        for (int rp = 0; rp < 8; ++rp) {
            const int r0 = 2 * rp;
            const int rowb = (r0 & 3) + 8 * (r0 >> 2) + 4 * lh;   // r0 even -> r0&3 in {0,2}
            float p0 = __builtin_amdgcn_exp2f(fmaf(sacc0[r0],     CSC, mb0));
            float p1 = __builtin_amdgcn_exp2f(fmaf(sacc0[r0 + 1], CSC, mb0));
            float p2 = __builtin_amdgcn_exp2f(fmaf(sacc1[r0],     CSC, mb1));
            float p3 = __builtin_amdgcn_exp2f(fmaf(sacc1[r0 + 1], CSC, mb1));
            lpart[r0]     += p0 + p2;
            lpart[r0 + 1] += p1 + p3;
            unsigned ua = cvt_pk_bf16(p0, p1);
            unsigned ub = cvt_pk_bf16(p2, p3);
            int base0 = (prow + rowb) * 72 + l31;
            Ps[base0]           = (ushort_t)ua;          // ct=0, row rowb
            Ps[base0 + 72]      = (ushort_t)(ua >> 16);  // ct=0, row rowb+1
            Ps[base0 + 32]      = (ushort_t)ub;          // ct=1 (key+32), row rowb
            Ps[base0 + 72 + 32] = (ushort_t)(ub >> 16);  // ct=1, row rowb+1
        }
        __builtin_amdgcn_sched_barrier(0);   // pin P-stores before PV reads

        // ---- O += P V : A = Ps rows (q), B = Vs rows (V^T, d) ----
        __builtin_amdgcn_s_setprio(1);
#pragma unroll
        for (int ks = 0; ks < 4; ++ks) {
            s16x8 pa  = *(const s16x8*)&Ps[(prow + l31) * 72 + ks * 16 + lh * 8];
            s16x8 vf0 = *(const s16x8*)&Vs[(l31)      * 72 + ks * 16 + lh * 8];
            s16x8 vf1 = *(const s16x8*)&Vs[(32 + l31) * 72 + ks * 16 + lh * 8];
            oacc0 = __builtin_amdgcn_mfma_f32_32x32x16_bf16(pa, vf0, oacc0, 0, 0, 0);
            oacc1 = __builtin_amdgcn_mfma_f32_32x32x16_bf16(pa, vf1, oacc1, 0, 0, 0);
        }
        __builtin_amdgcn_s_setprio(0);
    }

    // ---- epilogue: reduce row sums over the 32-lane half, normalize, store ----
#pragma unroll
    for (int rg = 0; rg < 16; ++rg) {
        lpart[rg] += __shfl_xor(lpart[rg], 1);
        lpart[rg] += __shfl_xor(lpart[rg], 2);
        lpart[rg] += __shfl_xor(lpart[rg], 4);
        lpart[rg] += __shfl_xor(lpart[rg], 8);
        lpart[rg] += __shfl_xor(lpart[rg], 16);   // stays within the 32-lane half
    }
    const size_t obase = ((size_t)b * SEQ + q0 + w * 32) * D_MODEL + h * DKH + l31;
#pragma unroll
    for (int rg = 0; rg < 16; ++rg) {
        const int qrow = (rg & 3) + 8 * (rg >> 2) + 4 * lh;
        const float inv = 1.f / lpart[rg];
        Ctx[obase + (size_t)qrow * D_MODEL]      = f2bf(oacc0[rg] * inv);
        Ctx[obase + (size_t)qrow * D_MODEL + 32] = f2bf(oacc1[rg] * inv);
    }
}

extern "C" void kernel_launch(void* const* d_in, const int* in_sizes, int n_in,
                              void* d_out, int out_size, void* d_ws, size_t ws_size,
                              hipStream_t stream) {
    const float* q    = (const float*)d_in[0];
    const float* k    = (const float*)d_in[1];
    const float* v    = (const float*)d_in[2];
    const int*   mask = (const int*)  d_in[3];
    const float* Wq   = (const float*)d_in[4];
    const float* bq   = (const float*)d_in[5];
    const float* Wk   = (const float*)d_in[6];
    const float* bk   = (const float*)d_in[7];
    const float* Wv   = (const float*)d_in[8];
    const float* bv   = (const float*)d_in[9];
    const float* Wo   = (const float*)d_in[10];
    const float* bo   = (const float*)d_in[11];
    float* out = (float*)d_out;

    char* ws = (char*)d_ws;
    ushort_t* Wqb  = (ushort_t*)(ws);                 //  0- 2 MB
    ushort_t* Wkb  = (ushort_t*)(ws + ( 2u << 20));   //  2- 4
    ushort_t* Wvb  = (ushort_t*)(ws + ( 4u << 20));   //  4- 6
    ushort_t* Wohi = (ushort_t*)(ws + ( 6u << 20));   //  6- 8
    ushort_t* Wolo = (ushort_t*)(ws + ( 8u << 20));   //  8-10
    float*    mb   = (float*)   (ws + (10u << 20));   // 10-12 (16KB used)
    ushort_t* qb   = (ushort_t*)(ws + (12u << 20));   // 12-20
    ushort_t* kb   = (ushort_t*)(ws + (20u << 20));   // 20-28
    ushort_t* vb   = (ushort_t*)(ws + (28u << 20));   // 28-36
    ushort_t* Qb   = (ushort_t*)(ws + (36u << 20));   // 36-44
    ushort_t* Kb   = (ushort_t*)(ws + (44u << 20));   // 44-52
    ushort_t* Vtb  = (ushort_t*)(ws + (52u << 20));   // 52-60
    ushort_t* Ctx  = qb;   // alias: qb free after gemm_qkv consumes it

    convert_all<<<2048, 256, 0, stream>>>(q, k, v, Wq, Wk, Wv, Wo, mask,
                                          qb, kb, vb, Wqb, Wkb, Wvb,
                                          Wohi, Wolo, mb);

    dim3 qkvgrid(D_MODEL / 128, TOK / 128, 3);
    gemm_qkv<<<qkvgrid, 256, 0, stream>>>(qb, kb, vb, Wqb, Wkb, Wvb,
                                          bq, bk, bv, Qb, Kb, Vtb);

    dim3 agrid(BATCH * NHEAD, SEQ / 128);   // x=bh -> XCD-local K/V reuse
    flash5<<<agrid, 256, 0, stream>>>(Qb, Kb, Vtb, mb, Ctx);

    dim3 ogrid(D_MODEL / 64, TOK / 128);
    gemm_out<<<ogrid, 256, 0, stream>>>(Ctx, Wohi, Wolo, bo, out);
}